// Round 10
// baseline (179.307 us; speedup 1.0000x reference)
//
#include <hip/hip_runtime.h>

#define NB 16
#define C  256
#define H  64
#define W  64
#define E  32
#define F  768
#define HW 4096
#define K5 2048
#define XROWS 4224   // 64 pad + 4096 + 64 pad

typedef __attribute__((ext_vector_type(4))) float f32x4;
typedef __attribute__((ext_vector_type(8))) short s16x8;

__device__ inline unsigned short to_bf16(float f) {
  union { float f; unsigned u; } v; v.f = f;
  unsigned u = v.u;
  u += 0x7fff + ((u >> 16) & 1);
  return (unsigned short)(u >> 16);
}

__device__ inline float from_bf16(unsigned short s) {
  union { unsigned u; float f; } v; v.u = ((unsigned)s) << 16;
  return v.f;
}

__device__ inline void gload16(const void* g, void* l) {
  __builtin_amdgcn_global_load_lds((const __attribute__((address_space(1))) unsigned int*)g,
                                   (__attribute__((address_space(3))) unsigned int*)l, 16, 0, 0);
}

// ---------------------------------------------------------------------------
// k_t1: t1b[nc][e*64+w] bf16 = sum_h x[nc][h][w] * p1[h][e].
// ---------------------------------------------------------------------------
__global__ __launch_bounds__(256) void k_t1(const float* __restrict__ x,
                                            const float* __restrict__ p1,
                                            unsigned short* __restrict__ t1b) {
  const int nc = blockIdx.x;
  const int tid = threadIdx.x;
  const int w = tid & 63;
  const int e0 = tid >> 6;  // 0..3
  __shared__ __align__(16) float p1t[32][68];  // 8.5 KB, p1t[e][h], +4 pad
  for (int i = tid; i < 2048; i += 256) {
    int h = i >> 5, e = i & 31;      // coalesced global read
    p1t[e][h] = p1[i];
  }
  __syncthreads();
  const float* xp = x + (size_t)nc * HW;
  float acc[8] = {0.f, 0.f, 0.f, 0.f, 0.f, 0.f, 0.f, 0.f};
#pragma unroll
  for (int hb = 0; hb < 4; ++hb) {
    float xv[16];
#pragma unroll
    for (int j = 0; j < 16; ++j) xv[j] = xp[(hb * 16 + j) * 64 + w];
#pragma unroll
    for (int i = 0; i < 8; ++i) {
      const float* pr = &p1t[e0 + 4 * i][hb * 16];
#pragma unroll
      for (int jb = 0; jb < 4; ++jb) {
        float4 pv = *(const float4*)(pr + jb * 4);
        acc[i] += xv[jb * 4 + 0] * pv.x + xv[jb * 4 + 1] * pv.y +
                  xv[jb * 4 + 2] * pv.z + xv[jb * 4 + 3] * pv.w;
      }
    }
  }
  unsigned short* op = t1b + (size_t)nc * 2048;
#pragma unroll
  for (int i = 0; i < 8; ++i) op[(e0 + 4 * i) * 64 + w] = to_bf16(acc[i]);
}

// ---------------------------------------------------------------------------
// k_t3: 9x9 depthwise conv on each (32,64) t1 plane, pad 4.
// ---------------------------------------------------------------------------
__global__ __launch_bounds__(256) void k_t3(const unsigned short* __restrict__ t1b,
                                            const float* __restrict__ p3,
                                            unsigned short* __restrict__ t3g) {
  const int nc = blockIdx.x;
  const int c = nc & 255;
  const int tid = threadIdx.x;
  __shared__ __align__(16) float t1s[40][76];  // 12160 B, zero borders
  for (int i = tid; i < 40 * 76; i += 256) (&t1s[0][0])[i] = 0.f;
  __syncthreads();
  {
    uint4 v = *(const uint4*)(t1b + (size_t)nc * 2048 + tid * 8);
    const unsigned short* vs = (const unsigned short*)&v;
    const int e = tid >> 3, w0 = (tid & 7) * 8;
    float f0[4], f1[4];
#pragma unroll
    for (int k = 0; k < 4; ++k) { f0[k] = from_bf16(vs[k]); f1[k] = from_bf16(vs[4 + k]); }
    *(float4*)&t1s[4 + e][4 + w0] = *(const float4*)f0;
    *(float4*)&t1s[4 + e][8 + w0] = *(const float4*)f1;
  }
  __syncthreads();
  unsigned short* plane = t3g + (size_t)nc * 2304;  // 36*64
  // zero halo rows 0,1,34,35
  if (tid < 32) {
    static const int zr[4] = {0, 1, 34, 35};
    int row = zr[tid >> 3], col = (tid & 7) * 8;
    uint4 z = make_uint4(0, 0, 0, 0);
    *(uint4*)(plane + row * 64 + col) = z;
  }
  const int e = tid >> 3, w0 = (tid & 7) * 8;
  const float* w3 = p3 + c * 81;
  float o[8];
#pragma unroll
  for (int k = 0; k < 8; ++k) o[k] = 0.f;
#pragma unroll
  for (int i = 0; i < 9; ++i) {
    float win[16];
    const float* r = &t1s[e + i][w0];
    *(float4*)&win[0]  = *(const float4*)(r);
    *(float4*)&win[4]  = *(const float4*)(r + 4);
    *(float4*)&win[8]  = *(const float4*)(r + 8);
    *(float4*)&win[12] = *(const float4*)(r + 12);
#pragma unroll
    for (int j = 0; j < 9; ++j) {
      float wt = w3[i * 9 + j];
#pragma unroll
      for (int k = 0; k < 8; ++k) o[k] += win[j + k] * wt;
    }
  }
  unsigned short ob[8];
#pragma unroll
  for (int k = 0; k < 8; ++k) ob[k] = to_bf16(o[k]);
  *(uint4*)(plane + (2 + e) * 64 + w0) = *(const uint4*)ob;
}

// ---------------------------------------------------------------------------
// k_t4k: (5,1) grouped conv (groups of 4 channels) over zero-padded t3 planes.
// ---------------------------------------------------------------------------
__global__ __launch_bounds__(256) void k_t4k(const unsigned short* __restrict__ t3g,
                                             const float* __restrict__ p4,
                                             unsigned short* __restrict__ t4b) {
  const int nc = blockIdx.x;
  const int c = nc & 255;
  const int tid = threadIdx.x;
  const int e = tid >> 3, w0 = (tid & 7) * 8;
  const float* w4 = p4 + c * 20;
  float acc[8];
#pragma unroll
  for (int k = 0; k < 8; ++k) acc[k] = 0.f;
#pragma unroll
  for (int ci = 0; ci < 4; ++ci) {
    const unsigned short* plane = t3g + (size_t)((nc & ~3) + ci) * 2304;
#pragma unroll
    for (int u = 0; u < 5; ++u) {
      uint4 v = *(const uint4*)(plane + (e + u) * 64 + w0);
      const unsigned short* vs = (const unsigned short*)&v;
      float wv = w4[ci * 5 + u];
#pragma unroll
      for (int k = 0; k < 8; ++k) acc[k] += from_bf16(vs[k]) * wv;
    }
  }
  unsigned short ob[8];
#pragma unroll
  for (int k = 0; k < 8; ++k) ob[k] = to_bf16(acc[k]);
  *(uint4*)(t4b + (size_t)nc * 2048 + e * 64 + w0) = *(const uint4*)ob;
}

// ---------------------------------------------------------------------------
// p5 [2048][768] f32 -> p5t [768][2048] bf16 (transpose + convert)
// ---------------------------------------------------------------------------
__global__ __launch_bounds__(256) void k_p5t(const float* __restrict__ p5,
                                             unsigned short* __restrict__ p5t) {
  const int f0 = blockIdx.x * 64;
  const int k0 = blockIdx.y * 64;
  const int tid = threadIdx.x;
  __shared__ __align__(16) unsigned short ls[64][264];
  int fl = tid & 63, k4 = tid >> 6;
  for (int i = 0; i < 16; ++i) {
    int kl = k4 * 16 + i;
    ls[fl][kl] = to_bf16(p5[(size_t)(k0 + kl) * F + f0 + fl]);
  }
  __syncthreads();
#pragma unroll
  for (int j = 0; j < 2; ++j) {
    int chunk = tid + 256 * j;
    int row = chunk >> 3, slot = chunk & 7;
    *(uint4*)(p5t + (size_t)(f0 + row) * K5 + k0 + slot * 8) = *(const uint4*)&ls[row][slot * 8];
  }
}

// ---------------------------------------------------------------------------
// x [n][c][h][w] f32 -> xt [n][64 + h*64+w + 64][c] bf16, zero pads
// ---------------------------------------------------------------------------
__global__ __launch_bounds__(256) void k_xt(const float* __restrict__ x,
                                            unsigned short* __restrict__ xt) {
  const int hi = blockIdx.x;   // 0..65
  const int n = blockIdx.y;
  const int tid = threadIdx.x;
  unsigned short* dst = xt + ((size_t)n * XROWS + hi * 64) * C;
  if (hi == 0 || hi == 65) {
    uint4 z = make_uint4(0, 0, 0, 0);
    uint4* d4 = (uint4*)dst;
#pragma unroll
    for (int i = 0; i < 8; ++i) d4[tid + 256 * i] = z;
    return;
  }
  const int h = hi - 1;
  __shared__ __align__(16) unsigned short ls[64][264];
  const float* xp = x + ((size_t)n * C) * HW + h * 64;
  int w = tid & 63, c4 = tid >> 6;
  for (int i = 0; i < 64; ++i) {
    int c = c4 * 64 + i;
    ls[w][c] = to_bf16(xp[(size_t)c * HW + w]);
  }
  __syncthreads();
#pragma unroll
  for (int j = 0; j < 8; ++j) {
    int chunk = tid + 256 * j;          // 2048 chunks of 16B
    int row = chunk >> 5, slot = chunk & 31;
    *(uint4*)(dst + row * C + slot * 8) = *(const uint4*)&ls[row][slot * 8];
  }
}

// ---------------------------------------------------------------------------
// k_t5m: t5[4096][768] f32 = t4b[4096][2048]bf16 x p5t^T.  64x64 tile,
// single-buffer 2-barrier structure, XCD-swizzled 1D grid (768 blocks).
// ---------------------------------------------------------------------------
__global__ __launch_bounds__(256) void k_t5m(const unsigned short* __restrict__ A,
                                             const unsigned short* __restrict__ Bt,
                                             float* __restrict__ Cout) {
  const int bid = blockIdx.x;
  const int wg = (bid & 7) * 96 + (bid >> 3);   // bijective: 768 = 8*96
  const int nt = wg % 12;
  const int mt = wg / 12;
  const int n0 = nt * 64;
  const int m0 = mt * 64;
  const int tid = threadIdx.x;
  const int lane = tid & 63;
  const int wave = tid >> 6;
  const int wm = wave >> 1, wn = wave & 1;
  __shared__ __align__(16) short As[4096];
  __shared__ __align__(16) short Bs[4096];
  f32x4 acc[2][2] = {};
  const int lr = lane >> 3;
  const int ls = lane & 7;

  for (int k0 = 0; k0 < K5; k0 += 64) {
#pragma unroll
    for (int i = 0; i < 2; ++i) {
      int inst = wave * 2 + i;       // 0..7
      int r = inst * 8 + lr;         // 0..63
      int sw = ls ^ (r & 7);
      gload16((const char*)(A + (size_t)(m0 + r) * K5 + k0) + sw * 16,
              (char*)As + inst * 1024);
      gload16((const char*)(Bt + (size_t)(n0 + r) * K5 + k0) + sw * 16,
              (char*)Bs + inst * 1024);
    }
    __syncthreads();
#pragma unroll
    for (int kh = 0; kh < 2; ++kh) {
      s16x8 af[2], bf[2];
#pragma unroll
      for (int mi = 0; mi < 2; ++mi) {
        int row = wm * 32 + mi * 16 + (lane & 15);
        int byte = (row * 128 + kh * 64 + (lane >> 4) * 16) ^ ((row & 7) << 4);
        af[mi] = *(const s16x8*)((const char*)As + byte);
      }
#pragma unroll
      for (int ni = 0; ni < 2; ++ni) {
        int row = wn * 32 + ni * 16 + (lane & 15);
        int byte = (row * 128 + kh * 64 + (lane >> 4) * 16) ^ ((row & 7) << 4);
        bf[ni] = *(const s16x8*)((const char*)Bs + byte);
      }
#pragma unroll
      for (int mi = 0; mi < 2; ++mi)
#pragma unroll
        for (int ni = 0; ni < 2; ++ni)
          acc[mi][ni] = __builtin_amdgcn_mfma_f32_16x16x32_bf16(af[mi], bf[ni], acc[mi][ni], 0, 0, 0);
    }
    __syncthreads();
  }
#pragma unroll
  for (int mi = 0; mi < 2; ++mi) {
    int rbase = m0 + wm * 32 + mi * 16 + (lane >> 4) * 4;
#pragma unroll
    for (int ni = 0; ni < 2; ++ni) {
      int col = n0 + wn * 32 + ni * 16 + (lane & 15);
#pragma unroll
      for (int q = 0; q < 4; ++q)
        Cout[(size_t)(rbase + q) * F + col] = acc[mi][ni][q];
    }
  }
}

// ---------------------------------------------------------------------------
// k_t6: t5 f32 -> 3-tap dw conv (original f order) -> scale -> bf16 in f' order
// f' = kk*256 + c2  (f = 3*c2 + kk)
// ---------------------------------------------------------------------------
__global__ __launch_bounds__(256) void k_t6(const float* __restrict__ t5,
                                            const float* __restrict__ p6,
                                            unsigned short* __restrict__ t6b) {
  int idx = blockIdx.x * 256 + threadIdx.x;
  if (idx >= NB * C * F) return;
  int fp = idx % F;
  int nc = idx / F;
  int c = nc & 255;
  int c2 = fp & 255;
  int kk = fp >> 8;
  int f = 3 * c2 + kk;
  const float* row = t5 + (size_t)nc * F;
  const float* wt = p6 + c * 3;
  float acc = row[f] * wt[1];
  if (f > 0) acc += row[f - 1] * wt[0];
  if (f < F - 1) acc += row[f + 1] * wt[2];
  t6b[idx] = to_bf16(acc * 0.03608439182435161f);
}

// ---------------------------------------------------------------------------
// k_outm: out[n][256][4096] f32 = t6b[n][256][768] x B' (from xt, shifted
// rows). 128x128 tile, single-buffer 2-barrier structure, XCD-swizzled 1D
// grid, LDS-transpose epilogue for fully-coalesced float4 stores.
// ---------------------------------------------------------------------------
__global__ __launch_bounds__(256) void k_outm(const unsigned short* __restrict__ t6b,
                                              const unsigned short* __restrict__ xt,
                                              float* __restrict__ outp) {
  const int bid = blockIdx.x;
  const int wg = (bid & 7) * 128 + (bid >> 3);  // bijective: 1024 = 8*128
  const int p0 = (wg & 31) * 128;               // p fastest
  const int m0 = ((wg >> 5) & 1) * 128;
  const int n  = wg >> 6;                       // n slowest: XCD gets ~2 n-slices
  const int tid = threadIdx.x;
  const int lane = tid & 63;
  const int wave = tid >> 6;
  const int wm = wave >> 1, wn = wave & 1;
  __shared__ __align__(16) short As[8192];
  __shared__ __align__(16) short Bs[8192];
  f32x4 acc[4][4] = {};
  const int lr = lane >> 3;
  const int ls = lane & 7;
  const unsigned short* Abase = t6b + (size_t)(n * C) * F;
  const unsigned short* Xbase = xt + (size_t)n * XROWS * C;

  for (int kt = 0; kt < 12; ++kt) {
    int k0 = kt * 64;
    int kk = k0 >> 8;
    int c20 = k0 & 255;
#pragma unroll
    for (int i = 0; i < 4; ++i) {
      int inst = wave * 4 + i;
      int r = inst * 8 + lr;
      int sw = ls ^ (r & 7);
      gload16((const char*)(Abase + (size_t)(m0 + r) * F + k0) + sw * 16,
              (char*)As + inst * 1024);
      gload16((const char*)(Xbase + (size_t)(p0 + r + (kk << 6)) * C + c20) + sw * 16,
              (char*)Bs + inst * 1024);
    }
    __syncthreads();
#pragma unroll
    for (int kh = 0; kh < 2; ++kh) {
      s16x8 af[4], bf[4];
#pragma unroll
      for (int mi = 0; mi < 4; ++mi) {
        int row = wm * 64 + mi * 16 + (lane & 15);
        int byte = (row * 128 + kh * 64 + (lane >> 4) * 16) ^ ((row & 7) << 4);
        af[mi] = *(const s16x8*)((const char*)As + byte);
      }
#pragma unroll
      for (int ni = 0; ni < 4; ++ni) {
        int row = wn * 64 + ni * 16 + (lane & 15);
        int byte = (row * 128 + kh * 64 + (lane >> 4) * 16) ^ ((row & 7) << 4);
        bf[ni] = *(const s16x8*)((const char*)Bs + byte);
      }
#pragma unroll
      for (int mi = 0; mi < 4; ++mi)
#pragma unroll
        for (int ni = 0; ni < 4; ++ni)
          acc[mi][ni] = __builtin_amdgcn_mfma_f32_16x16x32_bf16(af[mi], bf[ni], acc[mi][ni], 0, 0, 0);
    }
    __syncthreads();
  }
  // Epilogue: per mi, dump a 32x128 f32 slab to LDS, then coalesced float4
  // stores (1 KB contiguous per wave-instr). Global row for slab row s:
  // m0 + mi*16 + (s>>4)*64 + (s&15); slab row s = wm*16 + (lane>>4)*4 + q.
  float* obase = outp + (size_t)(n * C) * HW;
  float* lsf = (float*)As;  // 16 KB slab
  const int s_w = tid >> 3;
  const int c_w = (tid & 7) * 16;
#pragma unroll
  for (int mi = 0; mi < 4; ++mi) {
    __syncthreads();
#pragma unroll
    for (int ni = 0; ni < 4; ++ni) {
      int srow = wm * 16 + (lane >> 4) * 4;
      int col = wn * 64 + ni * 16 + (lane & 15);
#pragma unroll
      for (int q = 0; q < 4; ++q)
        lsf[(srow + q) * 128 + col] = acc[mi][ni][q];
    }
    __syncthreads();
    int grow = m0 + mi * 16 + (s_w >> 4) * 64 + (s_w & 15);
    float* orow = obase + (size_t)grow * HW + p0 + c_w;
    const float* lrow = lsf + s_w * 128 + c_w;
#pragma unroll
    for (int v = 0; v < 4; ++v)
      *(float4*)(orow + v * 4) = *(const float4*)(lrow + v * 4);
  }
}

extern "C" void kernel_launch(void* const* d_in, const int* in_sizes, int n_in,
                              void* d_out, int out_size, void* d_ws, size_t ws_size,
                              hipStream_t stream) {
  (void)in_sizes; (void)n_in; (void)out_size; (void)ws_size;
  const float* x  = (const float*)d_in[0];
  const float* p1 = (const float*)d_in[1];
  const float* p3 = (const float*)d_in[2];
  const float* p4 = (const float*)d_in[3];
  const float* p5 = (const float*)d_in[4];
  const float* p6 = (const float*)d_in[5];
  float* out = (float*)d_out;

  char* ws = (char*)d_ws;
  // Lifetime-overlaid workspace (peak 51.4 MB):
  //  [0      , 18.87M): t3g  (k_t3 -> k_t4k); then t6b at [0, 6.29M) (k_t6 ->)
  //                      and xt at [6.29M, 40.89M) (k_xt -> k_outm)
  //  [18.87M , 35.65M): t1b  (k_t1 -> k_t3); then t4b (k_t4k -> k_t5m)
  //  [35.65M , 38.80M): p5t  (k_p5t -> k_t5m)
  //  [38.80M , 51.38M): t5   (k_t5m -> k_t6)
  unsigned short* t3g = (unsigned short*)ws;
  unsigned short* t1b = (unsigned short*)(ws + 18874368);
  unsigned short* t4b = (unsigned short*)(ws + 18874368);
  unsigned short* p5t = (unsigned short*)(ws + 35651584);
  float*          t5  = (float*)(ws + 38797312);
  unsigned short* t6b = (unsigned short*)ws;
  unsigned short* xt  = (unsigned short*)(ws + 6291456);

  k_t1 <<<dim3(NB * C), 256, 0, stream>>>(x, p1, t1b);
  k_t3 <<<dim3(NB * C), 256, 0, stream>>>(t1b, p3, t3g);
  k_t4k<<<dim3(NB * C), 256, 0, stream>>>(t3g, p4, t4b);
  k_p5t<<<dim3(12, 32), 256, 0, stream>>>(p5, p5t);
  k_t5m<<<dim3(768), 256, 0, stream>>>(t4b, p5t, t5);
  k_t6 <<<dim3((NB * C * F + 255) / 256), 256, 0, stream>>>(t5, p6, t6b);
  k_xt <<<dim3(66, NB), 256, 0, stream>>>(x, xt);
  k_outm<<<dim3(1024), 256, 0, stream>>>(t6b, xt, out);
}

// Round 11
// 160.760 us; speedup vs baseline: 1.1154x; 1.1154x over previous
//
#include <hip/hip_runtime.h>

#define NB 16
#define C  256
#define H  64
#define W  64
#define E  32
#define F  768
#define HW 4096
#define K5 2048
#define XROWS 4224   // 64 pad + 4096 + 64 pad

typedef __attribute__((ext_vector_type(4))) float f32x4;
typedef __attribute__((ext_vector_type(16))) float f32x16;
typedef __attribute__((ext_vector_type(8))) short s16x8;

__device__ inline unsigned short to_bf16(float f) {
  union { float f; unsigned u; } v; v.f = f;
  unsigned u = v.u;
  u += 0x7fff + ((u >> 16) & 1);
  return (unsigned short)(u >> 16);
}

__device__ inline float from_bf16(unsigned short s) {
  union { unsigned u; float f; } v; v.u = ((unsigned)s) << 16;
  return v.f;
}

__device__ inline void gload16(const void* g, void* l) {
  __builtin_amdgcn_global_load_lds((const __attribute__((address_space(1))) unsigned int*)g,
                                   (__attribute__((address_space(3))) unsigned int*)l, 16, 0, 0);
}

// ---------------------------------------------------------------------------
// k_t1: t1b[nc][e*64+w] bf16 = sum_h x[nc][h][w] * p1[h][e].
// ---------------------------------------------------------------------------
__global__ __launch_bounds__(256) void k_t1(const float* __restrict__ x,
                                            const float* __restrict__ p1,
                                            unsigned short* __restrict__ t1b) {
  const int nc = blockIdx.x;
  const int tid = threadIdx.x;
  const int w = tid & 63;
  const int e0 = tid >> 6;  // 0..3
  __shared__ __align__(16) float p1t[32][68];  // 8.5 KB, p1t[e][h], +4 pad
  for (int i = tid; i < 2048; i += 256) {
    int h = i >> 5, e = i & 31;      // coalesced global read
    p1t[e][h] = p1[i];
  }
  __syncthreads();
  const float* xp = x + (size_t)nc * HW;
  float acc[8] = {0.f, 0.f, 0.f, 0.f, 0.f, 0.f, 0.f, 0.f};
#pragma unroll
  for (int hb = 0; hb < 4; ++hb) {
    float xv[16];
#pragma unroll
    for (int j = 0; j < 16; ++j) xv[j] = xp[(hb * 16 + j) * 64 + w];
#pragma unroll
    for (int i = 0; i < 8; ++i) {
      const float* pr = &p1t[e0 + 4 * i][hb * 16];
#pragma unroll
      for (int jb = 0; jb < 4; ++jb) {
        float4 pv = *(const float4*)(pr + jb * 4);
        acc[i] += xv[jb * 4 + 0] * pv.x + xv[jb * 4 + 1] * pv.y +
                  xv[jb * 4 + 2] * pv.z + xv[jb * 4 + 3] * pv.w;
      }
    }
  }
  unsigned short* op = t1b + (size_t)nc * 2048;
#pragma unroll
  for (int i = 0; i < 8; ++i) op[(e0 + 4 * i) * 64 + w] = to_bf16(acc[i]);
}

// ---------------------------------------------------------------------------
// k_t3: 9x9 depthwise conv on each (32,64) t1 plane, pad 4.
// ---------------------------------------------------------------------------
__global__ __launch_bounds__(256) void k_t3(const unsigned short* __restrict__ t1b,
                                            const float* __restrict__ p3,
                                            unsigned short* __restrict__ t3g) {
  const int nc = blockIdx.x;
  const int c = nc & 255;
  const int tid = threadIdx.x;
  __shared__ __align__(16) float t1s[40][76];  // 12160 B, zero borders
  for (int i = tid; i < 40 * 76; i += 256) (&t1s[0][0])[i] = 0.f;
  __syncthreads();
  {
    uint4 v = *(const uint4*)(t1b + (size_t)nc * 2048 + tid * 8);
    const unsigned short* vs = (const unsigned short*)&v;
    const int e = tid >> 3, w0 = (tid & 7) * 8;
    float f0[4], f1[4];
#pragma unroll
    for (int k = 0; k < 4; ++k) { f0[k] = from_bf16(vs[k]); f1[k] = from_bf16(vs[4 + k]); }
    *(float4*)&t1s[4 + e][4 + w0] = *(const float4*)f0;
    *(float4*)&t1s[4 + e][8 + w0] = *(const float4*)f1;
  }
  __syncthreads();
  unsigned short* plane = t3g + (size_t)nc * 2304;  // 36*64
  // zero halo rows 0,1,34,35
  if (tid < 32) {
    static const int zr[4] = {0, 1, 34, 35};
    int row = zr[tid >> 3], col = (tid & 7) * 8;
    uint4 z = make_uint4(0, 0, 0, 0);
    *(uint4*)(plane + row * 64 + col) = z;
  }
  const int e = tid >> 3, w0 = (tid & 7) * 8;
  const float* w3 = p3 + c * 81;
  float o[8];
#pragma unroll
  for (int k = 0; k < 8; ++k) o[k] = 0.f;
#pragma unroll
  for (int i = 0; i < 9; ++i) {
    float win[16];
    const float* r = &t1s[e + i][w0];
    *(float4*)&win[0]  = *(const float4*)(r);
    *(float4*)&win[4]  = *(const float4*)(r + 4);
    *(float4*)&win[8]  = *(const float4*)(r + 8);
    *(float4*)&win[12] = *(const float4*)(r + 12);
#pragma unroll
    for (int j = 0; j < 9; ++j) {
      float wt = w3[i * 9 + j];
#pragma unroll
      for (int k = 0; k < 8; ++k) o[k] += win[j + k] * wt;
    }
  }
  unsigned short ob[8];
#pragma unroll
  for (int k = 0; k < 8; ++k) ob[k] = to_bf16(o[k]);
  *(uint4*)(plane + (2 + e) * 64 + w0) = *(const uint4*)ob;
}

// ---------------------------------------------------------------------------
// k_t4k: (5,1) grouped conv (groups of 4 channels) over zero-padded t3 planes.
// ---------------------------------------------------------------------------
__global__ __launch_bounds__(256) void k_t4k(const unsigned short* __restrict__ t3g,
                                             const float* __restrict__ p4,
                                             unsigned short* __restrict__ t4b) {
  const int nc = blockIdx.x;
  const int c = nc & 255;
  const int tid = threadIdx.x;
  const int e = tid >> 3, w0 = (tid & 7) * 8;
  const float* w4 = p4 + c * 20;
  float acc[8];
#pragma unroll
  for (int k = 0; k < 8; ++k) acc[k] = 0.f;
#pragma unroll
  for (int ci = 0; ci < 4; ++ci) {
    const unsigned short* plane = t3g + (size_t)((nc & ~3) + ci) * 2304;
#pragma unroll
    for (int u = 0; u < 5; ++u) {
      uint4 v = *(const uint4*)(plane + (e + u) * 64 + w0);
      const unsigned short* vs = (const unsigned short*)&v;
      float wv = w4[ci * 5 + u];
#pragma unroll
      for (int k = 0; k < 8; ++k) acc[k] += from_bf16(vs[k]) * wv;
    }
  }
  unsigned short ob[8];
#pragma unroll
  for (int k = 0; k < 8; ++k) ob[k] = to_bf16(acc[k]);
  *(uint4*)(t4b + (size_t)nc * 2048 + e * 64 + w0) = *(const uint4*)ob;
}

// ---------------------------------------------------------------------------
// p5 [2048][768] f32 -> p5t [768][2048] bf16 (transpose + convert)
// ---------------------------------------------------------------------------
__global__ __launch_bounds__(256) void k_p5t(const float* __restrict__ p5,
                                             unsigned short* __restrict__ p5t) {
  const int f0 = blockIdx.x * 64;
  const int k0 = blockIdx.y * 64;
  const int tid = threadIdx.x;
  __shared__ __align__(16) unsigned short ls[64][264];
  int fl = tid & 63, k4 = tid >> 6;
  for (int i = 0; i < 16; ++i) {
    int kl = k4 * 16 + i;
    ls[fl][kl] = to_bf16(p5[(size_t)(k0 + kl) * F + f0 + fl]);
  }
  __syncthreads();
#pragma unroll
  for (int j = 0; j < 2; ++j) {
    int chunk = tid + 256 * j;
    int row = chunk >> 3, slot = chunk & 7;
    *(uint4*)(p5t + (size_t)(f0 + row) * K5 + k0 + slot * 8) = *(const uint4*)&ls[row][slot * 8];
  }
}

// ---------------------------------------------------------------------------
// x [n][c][h][w] f32 -> xt [n][64 + h*64+w + 64][c] bf16, zero pads
// ---------------------------------------------------------------------------
__global__ __launch_bounds__(256) void k_xt(const float* __restrict__ x,
                                            unsigned short* __restrict__ xt) {
  const int hi = blockIdx.x;   // 0..65
  const int n = blockIdx.y;
  const int tid = threadIdx.x;
  unsigned short* dst = xt + ((size_t)n * XROWS + hi * 64) * C;
  if (hi == 0 || hi == 65) {
    uint4 z = make_uint4(0, 0, 0, 0);
    uint4* d4 = (uint4*)dst;
#pragma unroll
    for (int i = 0; i < 8; ++i) d4[tid + 256 * i] = z;
    return;
  }
  const int h = hi - 1;
  __shared__ __align__(16) unsigned short ls[64][264];
  const float* xp = x + ((size_t)n * C) * HW + h * 64;
  int w = tid & 63, c4 = tid >> 6;
  for (int i = 0; i < 64; ++i) {
    int c = c4 * 64 + i;
    ls[w][c] = to_bf16(xp[(size_t)c * HW + w]);
  }
  __syncthreads();
#pragma unroll
  for (int j = 0; j < 8; ++j) {
    int chunk = tid + 256 * j;          // 2048 chunks of 16B
    int row = chunk >> 5, slot = chunk & 31;
    *(uint4*)(dst + row * C + slot * 8) = *(const uint4*)&ls[row][slot * 8];
  }
}

// ---------------------------------------------------------------------------
// k_t5m: t5[4096][768] f32 = t4b[4096][2048]bf16 x p5t^T.  64x64 tile,
// 32x32x16 MFMA (1 frag/wave), single-buffer, XCD-swizzled grid.
// ---------------------------------------------------------------------------
__global__ __launch_bounds__(256) void k_t5m(const unsigned short* __restrict__ A,
                                             const unsigned short* __restrict__ Bt,
                                             float* __restrict__ Cout) {
  const int bid = blockIdx.x;
  const int wg = (bid & 7) * 96 + (bid >> 3);   // bijective: 768 = 8*96
  const int nt = wg % 12;
  const int mt = wg / 12;
  const int n0 = nt * 64;
  const int m0 = mt * 64;
  const int tid = threadIdx.x;
  const int lane = tid & 63;
  const int wave = tid >> 6;
  const int wm = wave >> 1, wn = wave & 1;
  __shared__ __align__(16) short As[4096];
  __shared__ __align__(16) short Bs[4096];
  f32x16 acc = {};
  const int lr = lane >> 3;
  const int ls = lane & 7;

  for (int k0 = 0; k0 < K5; k0 += 64) {
#pragma unroll
    for (int i = 0; i < 2; ++i) {
      int inst = wave * 2 + i;       // 0..7
      int r = inst * 8 + lr;         // 0..63
      int sw = ls ^ (r & 7);
      gload16((const char*)(A + (size_t)(m0 + r) * K5 + k0) + sw * 16,
              (char*)As + inst * 1024);
      gload16((const char*)(Bt + (size_t)(n0 + r) * K5 + k0) + sw * 16,
              (char*)Bs + inst * 1024);
    }
    __syncthreads();
#pragma unroll
    for (int kq = 0; kq < 4; ++kq) {
      int arow = wm * 32 + (lane & 31);
      int abyte = (arow * 128 + kq * 32 + ((lane >> 5) * 16)) ^ ((arow & 7) << 4);
      s16x8 af = *(const s16x8*)((const char*)As + abyte);
      int brow = wn * 32 + (lane & 31);
      int bbyte = (brow * 128 + kq * 32 + ((lane >> 5) * 16)) ^ ((brow & 7) << 4);
      s16x8 bf = *(const s16x8*)((const char*)Bs + bbyte);
      acc = __builtin_amdgcn_mfma_f32_32x32x16_bf16(af, bf, acc, 0, 0, 0);
    }
    __syncthreads();
  }
  const int col = n0 + wn * 32 + (lane & 31);
#pragma unroll
  for (int r = 0; r < 16; ++r) {
    int grow = m0 + wm * 32 + (r & 3) + 8 * (r >> 2) + 4 * (lane >> 5);
    Cout[(size_t)grow * F + col] = acc[r];
  }
}

// ---------------------------------------------------------------------------
// k_t6: t5 f32 -> 3-tap dw conv (original f order) -> scale -> bf16 in f' order
// f' = kk*256 + c2  (f = 3*c2 + kk)
// ---------------------------------------------------------------------------
__global__ __launch_bounds__(256) void k_t6(const float* __restrict__ t5,
                                            const float* __restrict__ p6,
                                            unsigned short* __restrict__ t6b) {
  int idx = blockIdx.x * 256 + threadIdx.x;
  if (idx >= NB * C * F) return;
  int fp = idx % F;
  int nc = idx / F;
  int c = nc & 255;
  int c2 = fp & 255;
  int kk = fp >> 8;
  int f = 3 * c2 + kk;
  const float* row = t5 + (size_t)nc * F;
  const float* wt = p6 + c * 3;
  float acc = row[f] * wt[1];
  if (f > 0) acc += row[f - 1] * wt[0];
  if (f < F - 1) acc += row[f + 1] * wt[2];
  t6b[idx] = to_bf16(acc * 0.03608439182435161f);
}

// ---------------------------------------------------------------------------
// k_outm: out[n][256][4096] f32 = t6b[n][256][768] x B' (from xt, shifted
// rows). 256x256 tile, 512 threads / 8 waves (wave-tile 128x64), 32x32x16
// MFMA, double-buffered 128 KB LDS, counted-vmcnt depth-1 prefetch, raw
// barriers. Grid 256 blocks = 1/CU, XCD-swizzled (p fastest, n slowest).
// ---------------------------------------------------------------------------
__global__ __launch_bounds__(512, 2) void k_outm(const unsigned short* __restrict__ t6b,
                                                 const unsigned short* __restrict__ xt,
                                                 float* __restrict__ outp) {
  const int bid = blockIdx.x;
  const int wg = (bid & 7) * 32 + (bid >> 3);   // bijective: 256 = 8*32
  const int p0 = (wg & 15) * 256;               // 16 p-tiles
  const int n  = wg >> 4;                       // 16 n
  const int tid = threadIdx.x;
  const int lane = tid & 63;
  const int wid = tid >> 6;                     // 0..7
  const int wm = wid >> 2;                      // 0..1  (M half: 128 rows)
  const int wn = wid & 3;                       // 0..3  (N quarter: 64 cols)
  __shared__ __align__(16) short As[2][16384];  // 256x64 bf16 per buf (32 KB)
  __shared__ __align__(16) short Bs[2][16384];
  f32x16 acc[4][2] = {};
  const unsigned short* Abase = t6b + (size_t)(n * C) * F;
  const unsigned short* Xbase = xt + (size_t)n * XROWS * C;

  auto stage = [&](int b, int kt) {
    int k0 = kt * 64;
    int kk = k0 >> 8;
    int c20 = k0 & 255;
#pragma unroll
    for (int i = 0; i < 4; ++i) {
      int chunk = i * 512 + tid;    // 0..2047 chunks of 16 B (row r, slot sl)
      int r = chunk >> 3, sl = chunk & 7;
      int sw = sl ^ (r & 7);
      gload16((const char*)(Abase + (size_t)r * F + k0) + sw * 16,
              (char*)As[b] + chunk * 16);
      gload16((const char*)(Xbase + (size_t)(p0 + r + (kk << 6)) * C + c20) + sw * 16,
              (char*)Bs[b] + chunk * 16);
    }
  };

  stage(0, 0);
  asm volatile("s_waitcnt vmcnt(0)" ::: "memory");
  asm volatile("s_barrier" ::: "memory");
  int buf = 0;
  for (int kt = 0; kt < 12; ++kt) {
    if (kt < 11) {
      stage(buf ^ 1, kt + 1);
      asm volatile("s_waitcnt vmcnt(8)" ::: "memory");  // cur tile's 8 loads done
      asm volatile("s_barrier" ::: "memory");
    }
    // (kt==11: cur loads already drained by vmcnt(8) of kt==10 + barrier)
#pragma unroll
    for (int kq = 0; kq < 4; ++kq) {
      s16x8 af[4], bf[2];
#pragma unroll
      for (int mi = 0; mi < 4; ++mi) {
        int row = wm * 128 + mi * 32 + (lane & 31);
        int byte = (row * 128 + kq * 32 + ((lane >> 5) * 16)) ^ ((row & 7) << 4);
        af[mi] = *(const s16x8*)((const char*)As[buf] + byte);
      }
#pragma unroll
      for (int ni = 0; ni < 2; ++ni) {
        int row = wn * 64 + ni * 32 + (lane & 31);
        int byte = (row * 128 + kq * 32 + ((lane >> 5) * 16)) ^ ((row & 7) << 4);
        bf[ni] = *(const s16x8*)((const char*)Bs[buf] + byte);
      }
#pragma unroll
      for (int mi = 0; mi < 4; ++mi)
#pragma unroll
        for (int ni = 0; ni < 2; ++ni)
          acc[mi][ni] = __builtin_amdgcn_mfma_f32_32x32x16_bf16(af[mi], bf[ni], acc[mi][ni], 0, 0, 0);
    }
    asm volatile("s_waitcnt lgkmcnt(0)" ::: "memory");
    asm volatile("s_barrier" ::: "memory");
    buf ^= 1;
  }
  float* obase = outp + (size_t)(n * C) * HW;
#pragma unroll
  for (int mi = 0; mi < 4; ++mi) {
#pragma unroll
    for (int ni = 0; ni < 2; ++ni) {
      int gcol = p0 + wn * 64 + ni * 32 + (lane & 31);
#pragma unroll
      for (int r = 0; r < 16; ++r) {
        int grow = wm * 128 + mi * 32 + (r & 3) + 8 * (r >> 2) + 4 * (lane >> 5);
        obase[(size_t)grow * HW + gcol] = acc[mi][ni][r];
      }
    }
  }
}

extern "C" void kernel_launch(void* const* d_in, const int* in_sizes, int n_in,
                              void* d_out, int out_size, void* d_ws, size_t ws_size,
                              hipStream_t stream) {
  (void)in_sizes; (void)n_in; (void)out_size; (void)ws_size;
  const float* x  = (const float*)d_in[0];
  const float* p1 = (const float*)d_in[1];
  const float* p3 = (const float*)d_in[2];
  const float* p4 = (const float*)d_in[3];
  const float* p5 = (const float*)d_in[4];
  const float* p6 = (const float*)d_in[5];
  float* out = (float*)d_out;

  char* ws = (char*)d_ws;
  // Lifetime-overlaid workspace (peak 51.4 MB):
  //  [0      , 18.87M): t3g  (k_t3 -> k_t4k); then t6b at [0, 6.29M) (k_t6 ->)
  //                      and xt at [6.29M, 40.89M) (k_xt -> k_outm)
  //  [18.87M , 35.65M): t1b  (k_t1 -> k_t3); then t4b (k_t4k -> k_t5m)
  //  [35.65M , 38.80M): p5t  (k_p5t -> k_t5m)
  //  [38.80M , 51.38M): t5   (k_t5m -> k_t6)
  unsigned short* t3g = (unsigned short*)ws;
  unsigned short* t1b = (unsigned short*)(ws + 18874368);
  unsigned short* t4b = (unsigned short*)(ws + 18874368);
  unsigned short* p5t = (unsigned short*)(ws + 35651584);
  float*          t5  = (float*)(ws + 38797312);
  unsigned short* t6b = (unsigned short*)ws;
  unsigned short* xt  = (unsigned short*)(ws + 6291456);

  k_t1 <<<dim3(NB * C), 256, 0, stream>>>(x, p1, t1b);
  k_t3 <<<dim3(NB * C), 256, 0, stream>>>(t1b, p3, t3g);
  k_t4k<<<dim3(NB * C), 256, 0, stream>>>(t3g, p4, t4b);
  k_p5t<<<dim3(12, 32), 256, 0, stream>>>(p5, p5t);
  k_t5m<<<dim3(768), 256, 0, stream>>>(t4b, p5t, t5);
  k_t6 <<<dim3((NB * C * F + 255) / 256), 256, 0, stream>>>(t5, p6, t6b);
  k_xt <<<dim3(66, NB), 256, 0, stream>>>(x, xt);
  k_outm<<<dim3(256), 512, 0, stream>>>(t6b, xt, out);
}

// Round 12
// 159.660 us; speedup vs baseline: 1.1231x; 1.0069x over previous
//
#include <hip/hip_runtime.h>

#define NB 16
#define C  256
#define H  64
#define W  64
#define E  32
#define F  768
#define HW 4096
#define K5 2048
#define XROWS 4224   // 64 pad + 4096 + 64 pad

typedef __attribute__((ext_vector_type(4))) float f32x4;
typedef __attribute__((ext_vector_type(16))) float f32x16;
typedef __attribute__((ext_vector_type(8))) short s16x8;

__device__ inline unsigned short to_bf16(float f) {
  union { float f; unsigned u; } v; v.f = f;
  unsigned u = v.u;
  u += 0x7fff + ((u >> 16) & 1);
  return (unsigned short)(u >> 16);
}

__device__ inline float from_bf16(unsigned short s) {
  union { unsigned u; float f; } v; v.u = ((unsigned)s) << 16;
  return v.f;
}

__device__ inline void gload16(const void* g, void* l) {
  __builtin_amdgcn_global_load_lds((const __attribute__((address_space(1))) unsigned int*)g,
                                   (__attribute__((address_space(3))) unsigned int*)l, 16, 0, 0);
}

// ---------------------------------------------------------------------------
// k_t1: t1b[nc][e*64+w] bf16 = sum_h x[nc][h][w] * p1[h][e].
// ---------------------------------------------------------------------------
__global__ __launch_bounds__(256) void k_t1(const float* __restrict__ x,
                                            const float* __restrict__ p1,
                                            unsigned short* __restrict__ t1b) {
  const int nc = blockIdx.x;
  const int tid = threadIdx.x;
  const int w = tid & 63;
  const int e0 = tid >> 6;  // 0..3
  __shared__ __align__(16) float p1t[32][68];  // 8.5 KB, p1t[e][h], +4 pad
  for (int i = tid; i < 2048; i += 256) {
    int h = i >> 5, e = i & 31;      // coalesced global read
    p1t[e][h] = p1[i];
  }
  __syncthreads();
  const float* xp = x + (size_t)nc * HW;
  float acc[8] = {0.f, 0.f, 0.f, 0.f, 0.f, 0.f, 0.f, 0.f};
#pragma unroll
  for (int hb = 0; hb < 4; ++hb) {
    float xv[16];
#pragma unroll
    for (int j = 0; j < 16; ++j) xv[j] = xp[(hb * 16 + j) * 64 + w];
#pragma unroll
    for (int i = 0; i < 8; ++i) {
      const float* pr = &p1t[e0 + 4 * i][hb * 16];
#pragma unroll
      for (int jb = 0; jb < 4; ++jb) {
        float4 pv = *(const float4*)(pr + jb * 4);
        acc[i] += xv[jb * 4 + 0] * pv.x + xv[jb * 4 + 1] * pv.y +
                  xv[jb * 4 + 2] * pv.z + xv[jb * 4 + 3] * pv.w;
      }
    }
  }
  unsigned short* op = t1b + (size_t)nc * 2048;
#pragma unroll
  for (int i = 0; i < 8; ++i) op[(e0 + 4 * i) * 64 + w] = to_bf16(acc[i]);
}

// ---------------------------------------------------------------------------
// k_t3: 9x9 depthwise conv on each (32,64) t1 plane, pad 4.
// ---------------------------------------------------------------------------
__global__ __launch_bounds__(256) void k_t3(const unsigned short* __restrict__ t1b,
                                            const float* __restrict__ p3,
                                            unsigned short* __restrict__ t3g) {
  const int nc = blockIdx.x;
  const int c = nc & 255;
  const int tid = threadIdx.x;
  __shared__ __align__(16) float t1s[40][76];  // 12160 B, zero borders
  for (int i = tid; i < 40 * 76; i += 256) (&t1s[0][0])[i] = 0.f;
  __syncthreads();
  {
    uint4 v = *(const uint4*)(t1b + (size_t)nc * 2048 + tid * 8);
    const unsigned short* vs = (const unsigned short*)&v;
    const int e = tid >> 3, w0 = (tid & 7) * 8;
    float f0[4], f1[4];
#pragma unroll
    for (int k = 0; k < 4; ++k) { f0[k] = from_bf16(vs[k]); f1[k] = from_bf16(vs[4 + k]); }
    *(float4*)&t1s[4 + e][4 + w0] = *(const float4*)f0;
    *(float4*)&t1s[4 + e][8 + w0] = *(const float4*)f1;
  }
  __syncthreads();
  unsigned short* plane = t3g + (size_t)nc * 2304;  // 36*64
  // zero halo rows 0,1,34,35
  if (tid < 32) {
    static const int zr[4] = {0, 1, 34, 35};
    int row = zr[tid >> 3], col = (tid & 7) * 8;
    uint4 z = make_uint4(0, 0, 0, 0);
    *(uint4*)(plane + row * 64 + col) = z;
  }
  const int e = tid >> 3, w0 = (tid & 7) * 8;
  const float* w3 = p3 + c * 81;
  float o[8];
#pragma unroll
  for (int k = 0; k < 8; ++k) o[k] = 0.f;
#pragma unroll
  for (int i = 0; i < 9; ++i) {
    float win[16];
    const float* r = &t1s[e + i][w0];
    *(float4*)&win[0]  = *(const float4*)(r);
    *(float4*)&win[4]  = *(const float4*)(r + 4);
    *(float4*)&win[8]  = *(const float4*)(r + 8);
    *(float4*)&win[12] = *(const float4*)(r + 12);
#pragma unroll
    for (int j = 0; j < 9; ++j) {
      float wt = w3[i * 9 + j];
#pragma unroll
      for (int k = 0; k < 8; ++k) o[k] += win[j + k] * wt;
    }
  }
  unsigned short ob[8];
#pragma unroll
  for (int k = 0; k < 8; ++k) ob[k] = to_bf16(o[k]);
  *(uint4*)(plane + (2 + e) * 64 + w0) = *(const uint4*)ob;
}

// ---------------------------------------------------------------------------
// k_t4k: (5,1) grouped conv (groups of 4 channels) over zero-padded t3 planes.
// ---------------------------------------------------------------------------
__global__ __launch_bounds__(256) void k_t4k(const unsigned short* __restrict__ t3g,
                                             const float* __restrict__ p4,
                                             unsigned short* __restrict__ t4b) {
  const int nc = blockIdx.x;
  const int c = nc & 255;
  const int tid = threadIdx.x;
  const int e = tid >> 3, w0 = (tid & 7) * 8;
  const float* w4 = p4 + c * 20;
  float acc[8];
#pragma unroll
  for (int k = 0; k < 8; ++k) acc[k] = 0.f;
#pragma unroll
  for (int ci = 0; ci < 4; ++ci) {
    const unsigned short* plane = t3g + (size_t)((nc & ~3) + ci) * 2304;
#pragma unroll
    for (int u = 0; u < 5; ++u) {
      uint4 v = *(const uint4*)(plane + (e + u) * 64 + w0);
      const unsigned short* vs = (const unsigned short*)&v;
      float wv = w4[ci * 5 + u];
#pragma unroll
      for (int k = 0; k < 8; ++k) acc[k] += from_bf16(vs[k]) * wv;
    }
  }
  unsigned short ob[8];
#pragma unroll
  for (int k = 0; k < 8; ++k) ob[k] = to_bf16(acc[k]);
  *(uint4*)(t4b + (size_t)nc * 2048 + e * 64 + w0) = *(const uint4*)ob;
}

// ---------------------------------------------------------------------------
// p5 [2048][768] f32 -> p5t [768][2048] bf16 (transpose + convert)
// ---------------------------------------------------------------------------
__global__ __launch_bounds__(256) void k_p5t(const float* __restrict__ p5,
                                             unsigned short* __restrict__ p5t) {
  const int f0 = blockIdx.x * 64;
  const int k0 = blockIdx.y * 64;
  const int tid = threadIdx.x;
  __shared__ __align__(16) unsigned short ls[64][264];
  int fl = tid & 63, k4 = tid >> 6;
  for (int i = 0; i < 16; ++i) {
    int kl = k4 * 16 + i;
    ls[fl][kl] = to_bf16(p5[(size_t)(k0 + kl) * F + f0 + fl]);
  }
  __syncthreads();
#pragma unroll
  for (int j = 0; j < 2; ++j) {
    int chunk = tid + 256 * j;
    int row = chunk >> 3, slot = chunk & 7;
    *(uint4*)(p5t + (size_t)(f0 + row) * K5 + k0 + slot * 8) = *(const uint4*)&ls[row][slot * 8];
  }
}

// ---------------------------------------------------------------------------
// x [n][c][h][w] f32 -> xt [n][64 + h*64+w + 64][c] bf16, zero pads
// ---------------------------------------------------------------------------
__global__ __launch_bounds__(256) void k_xt(const float* __restrict__ x,
                                            unsigned short* __restrict__ xt) {
  const int hi = blockIdx.x;   // 0..65
  const int n = blockIdx.y;
  const int tid = threadIdx.x;
  unsigned short* dst = xt + ((size_t)n * XROWS + hi * 64) * C;
  if (hi == 0 || hi == 65) {
    uint4 z = make_uint4(0, 0, 0, 0);
    uint4* d4 = (uint4*)dst;
#pragma unroll
    for (int i = 0; i < 8; ++i) d4[tid + 256 * i] = z;
    return;
  }
  const int h = hi - 1;
  __shared__ __align__(16) unsigned short ls[64][264];
  const float* xp = x + ((size_t)n * C) * HW + h * 64;
  int w = tid & 63, c4 = tid >> 6;
  for (int i = 0; i < 64; ++i) {
    int c = c4 * 64 + i;
    ls[w][c] = to_bf16(xp[(size_t)c * HW + w]);
  }
  __syncthreads();
#pragma unroll
  for (int j = 0; j < 8; ++j) {
    int chunk = tid + 256 * j;          // 2048 chunks of 16B
    int row = chunk >> 5, slot = chunk & 31;
    *(uint4*)(dst + row * C + slot * 8) = *(const uint4*)&ls[row][slot * 8];
  }
}

// ---------------------------------------------------------------------------
// k_t5m: t5[4096][768] f32 = t4b[4096][2048]bf16 x p5t^T.  64x64 tile,
// 32x32x16 MFMA (1 frag/wave), single-buffer, XCD-swizzled grid.
// ---------------------------------------------------------------------------
__global__ __launch_bounds__(256) void k_t5m(const unsigned short* __restrict__ A,
                                             const unsigned short* __restrict__ Bt,
                                             float* __restrict__ Cout) {
  const int bid = blockIdx.x;
  const int wg = (bid & 7) * 96 + (bid >> 3);   // bijective: 768 = 8*96
  const int nt = wg % 12;
  const int mt = wg / 12;
  const int n0 = nt * 64;
  const int m0 = mt * 64;
  const int tid = threadIdx.x;
  const int lane = tid & 63;
  const int wave = tid >> 6;
  const int wm = wave >> 1, wn = wave & 1;
  __shared__ __align__(16) short As[4096];
  __shared__ __align__(16) short Bs[4096];
  f32x16 acc = {};
  const int lr = lane >> 3;
  const int ls = lane & 7;

  for (int k0 = 0; k0 < K5; k0 += 64) {
#pragma unroll
    for (int i = 0; i < 2; ++i) {
      int inst = wave * 2 + i;       // 0..7
      int r = inst * 8 + lr;         // 0..63
      int sw = ls ^ (r & 7);
      gload16((const char*)(A + (size_t)(m0 + r) * K5 + k0) + sw * 16,
              (char*)As + inst * 1024);
      gload16((const char*)(Bt + (size_t)(n0 + r) * K5 + k0) + sw * 16,
              (char*)Bs + inst * 1024);
    }
    __syncthreads();
#pragma unroll
    for (int kq = 0; kq < 4; ++kq) {
      int arow = wm * 32 + (lane & 31);
      int abyte = (arow * 128 + kq * 32 + ((lane >> 5) * 16)) ^ ((arow & 7) << 4);
      s16x8 af = *(const s16x8*)((const char*)As + abyte);
      int brow = wn * 32 + (lane & 31);
      int bbyte = (brow * 128 + kq * 32 + ((lane >> 5) * 16)) ^ ((brow & 7) << 4);
      s16x8 bf = *(const s16x8*)((const char*)Bs + bbyte);
      acc = __builtin_amdgcn_mfma_f32_32x32x16_bf16(af, bf, acc, 0, 0, 0);
    }
    __syncthreads();
  }
  const int col = n0 + wn * 32 + (lane & 31);
#pragma unroll
  for (int r = 0; r < 16; ++r) {
    int grow = m0 + wm * 32 + (r & 3) + 8 * (r >> 2) + 4 * (lane >> 5);
    Cout[(size_t)grow * F + col] = acc[r];
  }
}

// ---------------------------------------------------------------------------
// k_t6: t5 f32 -> 3-tap dw conv (original f order) -> scale -> bf16 in f' order
// f' = kk*256 + c2  (f = 3*c2 + kk)
// ---------------------------------------------------------------------------
__global__ __launch_bounds__(256) void k_t6(const float* __restrict__ t5,
                                            const float* __restrict__ p6,
                                            unsigned short* __restrict__ t6b) {
  int idx = blockIdx.x * 256 + threadIdx.x;
  if (idx >= NB * C * F) return;
  int fp = idx % F;
  int nc = idx / F;
  int c = nc & 255;
  int c2 = fp & 255;
  int kk = fp >> 8;
  int f = 3 * c2 + kk;
  const float* row = t5 + (size_t)nc * F;
  const float* wt = p6 + c * 3;
  float acc = row[f] * wt[1];
  if (f > 0) acc += row[f - 1] * wt[0];
  if (f < F - 1) acc += row[f + 1] * wt[2];
  t6b[idx] = to_bf16(acc * 0.03608439182435161f);
}

// ---------------------------------------------------------------------------
// k_outm: out[n][256][4096] f32 = t6b[n][256][768] x B' (from xt, shifted
// rows). 256x256 tile, 512 thr / 8 waves (2M x 4N, wave-tile 128x64),
// 32x32x16 MFMA, 128 KB dbuf LDS. Per-K-tile 4-phase schedule (m201-style):
// each phase {6 ds_read || prefetch gloads (ph<2)} -> barrier -> lgkmcnt(0)
// -> setprio MFMA -> barrier; single vmcnt(0) drain at tile boundary.
// ---------------------------------------------------------------------------
__global__ __launch_bounds__(512, 1) void k_outm(const unsigned short* __restrict__ t6b,
                                                 const unsigned short* __restrict__ xt,
                                                 float* __restrict__ outp) {
  const int bid = blockIdx.x;
  const int wg = (bid & 7) * 32 + (bid >> 3);   // bijective: 256 = 8*32
  const int p0 = (wg & 15) * 256;               // 16 p-tiles
  const int n  = wg >> 4;                       // 16 n (same-n blocks same XCD)
  const int tid = threadIdx.x;
  const int lane = tid & 63;
  const int wid = tid >> 6;                     // 0..7
  const int wm = wid >> 2;                      // 0..1
  const int wn = wid & 3;                       // 0..3
  __shared__ __align__(16) short As[2][16384];  // 256x64 bf16 per buf
  __shared__ __align__(16) short Bs[2][16384];
  f32x16 acc[4][2] = {};
  const unsigned short* Abase = t6b + (size_t)(n * C) * F;
  const unsigned short* Xbase = xt + (size_t)n * XROWS * C;

  auto stageA = [&](int b, int kt, int i) {
    int chunk = i * 512 + tid;                  // 16 B chunks: row r, slot sl
    int r = chunk >> 3, sl = chunk & 7, sw = sl ^ (r & 7);
    gload16((const char*)(Abase + (size_t)r * F + kt * 64) + sw * 16,
            (char*)As[b] + chunk * 16);
  };
  auto stageB = [&](int b, int kt, int i) {
    int k0 = kt * 64;
    int kk = k0 >> 8, c20 = k0 & 255;
    int chunk = i * 512 + tid;
    int r = chunk >> 3, sl = chunk & 7, sw = sl ^ (r & 7);
    gload16((const char*)(Xbase + (size_t)(p0 + r + (kk << 6)) * C + c20) + sw * 16,
            (char*)Bs[b] + chunk * 16);
  };

  // prologue: stage tile 0 fully
#pragma unroll
  for (int i = 0; i < 4; ++i) { stageA(0, 0, i); stageB(0, 0, i); }
  asm volatile("s_waitcnt vmcnt(0)" ::: "memory");
  __builtin_amdgcn_s_barrier();

  int cur = 0;
  for (int kt = 0; kt < 12; ++kt) {
#pragma unroll
    for (int ph = 0; ph < 4; ++ph) {
      // ds-load this phase's k-substep fragments (6 x b128)
      s16x8 af[4], bf[2];
#pragma unroll
      for (int mi = 0; mi < 4; ++mi) {
        int row = wm * 128 + mi * 32 + (lane & 31);
        int byte = (row * 128 + ph * 32 + ((lane >> 5) * 16)) ^ ((row & 7) << 4);
        af[mi] = *(const s16x8*)((const char*)As[cur] + byte);
      }
#pragma unroll
      for (int ni = 0; ni < 2; ++ni) {
        int row = wn * 64 + ni * 32 + (lane & 31);
        int byte = (row * 128 + ph * 32 + ((lane >> 5) * 16)) ^ ((row & 7) << 4);
        bf[ni] = *(const s16x8*)((const char*)Bs[cur] + byte);
      }
      // prefetch next tile early (phases 0,1 -> full tile issued by mid-tile)
      if (kt < 11 && ph < 2) {
        stageA(cur ^ 1, kt + 1, ph * 2);
        stageA(cur ^ 1, kt + 1, ph * 2 + 1);
        stageB(cur ^ 1, kt + 1, ph * 2);
        stageB(cur ^ 1, kt + 1, ph * 2 + 1);
      }
      __builtin_amdgcn_s_barrier();
      asm volatile("s_waitcnt lgkmcnt(0)" ::: "memory");
      __builtin_amdgcn_sched_barrier(0);
      __builtin_amdgcn_s_setprio(1);
#pragma unroll
      for (int mi = 0; mi < 4; ++mi)
#pragma unroll
        for (int ni = 0; ni < 2; ++ni)
          acc[mi][ni] = __builtin_amdgcn_mfma_f32_32x32x16_bf16(af[mi], bf[ni], acc[mi][ni], 0, 0, 0);
      __builtin_amdgcn_s_setprio(0);
      if (ph == 3 && kt < 11)  // tile boundary: next buf fully landed
        asm volatile("s_waitcnt vmcnt(0)" ::: "memory");
      __builtin_amdgcn_s_barrier();
    }
    cur ^= 1;
  }
  float* obase = outp + (size_t)(n * C) * HW;
#pragma unroll
  for (int mi = 0; mi < 4; ++mi) {
#pragma unroll
    for (int ni = 0; ni < 2; ++ni) {
      int gcol = p0 + wn * 64 + ni * 32 + (lane & 31);
#pragma unroll
      for (int r = 0; r < 16; ++r) {
        int grow = wm * 128 + mi * 32 + (r & 3) + 8 * (r >> 2) + 4 * (lane >> 5);
        obase[(size_t)grow * HW + gcol] = acc[mi][ni][r];
      }
    }
  }
}

extern "C" void kernel_launch(void* const* d_in, const int* in_sizes, int n_in,
                              void* d_out, int out_size, void* d_ws, size_t ws_size,
                              hipStream_t stream) {
  (void)in_sizes; (void)n_in; (void)out_size; (void)ws_size;
  const float* x  = (const float*)d_in[0];
  const float* p1 = (const float*)d_in[1];
  const float* p3 = (const float*)d_in[2];
  const float* p4 = (const float*)d_in[3];
  const float* p5 = (const float*)d_in[4];
  const float* p6 = (const float*)d_in[5];
  float* out = (float*)d_out;

  char* ws = (char*)d_ws;
  // Lifetime-overlaid workspace (peak 51.4 MB):
  //  [0      , 18.87M): t3g  (k_t3 -> k_t4k); then t6b at [0, 6.29M) (k_t6 ->)
  //                      and xt at [6.29M, 40.89M) (k_xt -> k_outm)
  //  [18.87M , 35.65M): t1b  (k_t1 -> k_t3); then t4b (k_t4k -> k_t5m)
  //  [35.65M , 38.80M): p5t  (k_p5t -> k_t5m)
  //  [38.80M , 51.38M): t5   (k_t5m -> k_t6)
  unsigned short* t3g = (unsigned short*)ws;
  unsigned short* t1b = (unsigned short*)(ws + 18874368);
  unsigned short* t4b = (unsigned short*)(ws + 18874368);
  unsigned short* p5t = (unsigned short*)(ws + 35651584);
  float*          t5  = (float*)(ws + 38797312);
  unsigned short* t6b = (unsigned short*)ws;
  unsigned short* xt  = (unsigned short*)(ws + 6291456);

  k_t1 <<<dim3(NB * C), 256, 0, stream>>>(x, p1, t1b);
  k_t3 <<<dim3(NB * C), 256, 0, stream>>>(t1b, p3, t3g);
  k_t4k<<<dim3(NB * C), 256, 0, stream>>>(t3g, p4, t4b);
  k_p5t<<<dim3(12, 32), 256, 0, stream>>>(p5, p5t);
  k_t5m<<<dim3(768), 256, 0, stream>>>(t4b, p5t, t5);
  k_t6 <<<dim3((NB * C * F + 255) / 256), 256, 0, stream>>>(t5, p6, t6b);
  k_xt <<<dim3(66, NB), 256, 0, stream>>>(x, xt);
  k_outm<<<dim3(256), 512, 0, stream>>>(t6b, xt, out);
}

// Round 13
// 155.931 us; speedup vs baseline: 1.1499x; 1.0239x over previous
//
#include <hip/hip_runtime.h>

#define NB 16
#define C  256
#define H  64
#define W  64
#define E  32
#define F  768
#define HW 4096
#define K5 2048
#define XROWS 4224   // 64 pad + 4096 + 64 pad

typedef __attribute__((ext_vector_type(4))) float f32x4;
typedef __attribute__((ext_vector_type(16))) float f32x16;
typedef __attribute__((ext_vector_type(8))) short s16x8;

__device__ inline unsigned short to_bf16(float f) {
  union { float f; unsigned u; } v; v.f = f;
  unsigned u = v.u;
  u += 0x7fff + ((u >> 16) & 1);
  return (unsigned short)(u >> 16);
}

__device__ inline float from_bf16(unsigned short s) {
  union { unsigned u; float f; } v; v.u = ((unsigned)s) << 16;
  return v.f;
}

__device__ inline void gload16(const void* g, void* l) {
  __builtin_amdgcn_global_load_lds((const __attribute__((address_space(1))) unsigned int*)g,
                                   (__attribute__((address_space(3))) unsigned int*)l, 16, 0, 0);
}

// ---------------------------------------------------------------------------
// k_t1: t1b[nc][e*64+w] bf16 = sum_h x[nc][h][w] * p1[h][e].
// ---------------------------------------------------------------------------
__global__ __launch_bounds__(256) void k_t1(const float* __restrict__ x,
                                            const float* __restrict__ p1,
                                            unsigned short* __restrict__ t1b) {
  const int nc = blockIdx.x;
  const int tid = threadIdx.x;
  const int w = tid & 63;
  const int e0 = tid >> 6;  // 0..3
  __shared__ __align__(16) float p1t[32][68];  // 8.5 KB, p1t[e][h], +4 pad
  for (int i = tid; i < 2048; i += 256) {
    int h = i >> 5, e = i & 31;      // coalesced global read
    p1t[e][h] = p1[i];
  }
  __syncthreads();
  const float* xp = x + (size_t)nc * HW;
  float acc[8] = {0.f, 0.f, 0.f, 0.f, 0.f, 0.f, 0.f, 0.f};
#pragma unroll
  for (int hb = 0; hb < 4; ++hb) {
    float xv[16];
#pragma unroll
    for (int j = 0; j < 16; ++j) xv[j] = xp[(hb * 16 + j) * 64 + w];
#pragma unroll
    for (int i = 0; i < 8; ++i) {
      const float* pr = &p1t[e0 + 4 * i][hb * 16];
#pragma unroll
      for (int jb = 0; jb < 4; ++jb) {
        float4 pv = *(const float4*)(pr + jb * 4);
        acc[i] += xv[jb * 4 + 0] * pv.x + xv[jb * 4 + 1] * pv.y +
                  xv[jb * 4 + 2] * pv.z + xv[jb * 4 + 3] * pv.w;
      }
    }
  }
  unsigned short* op = t1b + (size_t)nc * 2048;
#pragma unroll
  for (int i = 0; i < 8; ++i) op[(e0 + 4 * i) * 64 + w] = to_bf16(acc[i]);
}

// ---------------------------------------------------------------------------
// k_t3: 9x9 depthwise conv on each (32,64) t1 plane, pad 4.
// ---------------------------------------------------------------------------
__global__ __launch_bounds__(256) void k_t3(const unsigned short* __restrict__ t1b,
                                            const float* __restrict__ p3,
                                            unsigned short* __restrict__ t3g) {
  const int nc = blockIdx.x;
  const int c = nc & 255;
  const int tid = threadIdx.x;
  __shared__ __align__(16) float t1s[40][76];  // 12160 B, zero borders
  for (int i = tid; i < 40 * 76; i += 256) (&t1s[0][0])[i] = 0.f;
  __syncthreads();
  {
    uint4 v = *(const uint4*)(t1b + (size_t)nc * 2048 + tid * 8);
    const unsigned short* vs = (const unsigned short*)&v;
    const int e = tid >> 3, w0 = (tid & 7) * 8;
    float f0[4], f1[4];
#pragma unroll
    for (int k = 0; k < 4; ++k) { f0[k] = from_bf16(vs[k]); f1[k] = from_bf16(vs[4 + k]); }
    *(float4*)&t1s[4 + e][4 + w0] = *(const float4*)f0;
    *(float4*)&t1s[4 + e][8 + w0] = *(const float4*)f1;
  }
  __syncthreads();
  unsigned short* plane = t3g + (size_t)nc * 2304;  // 36*64
  // zero halo rows 0,1,34,35
  if (tid < 32) {
    static const int zr[4] = {0, 1, 34, 35};
    int row = zr[tid >> 3], col = (tid & 7) * 8;
    uint4 z = make_uint4(0, 0, 0, 0);
    *(uint4*)(plane + row * 64 + col) = z;
  }
  const int e = tid >> 3, w0 = (tid & 7) * 8;
  const float* w3 = p3 + c * 81;
  float o[8];
#pragma unroll
  for (int k = 0; k < 8; ++k) o[k] = 0.f;
#pragma unroll
  for (int i = 0; i < 9; ++i) {
    float win[16];
    const float* r = &t1s[e + i][w0];
    *(float4*)&win[0]  = *(const float4*)(r);
    *(float4*)&win[4]  = *(const float4*)(r + 4);
    *(float4*)&win[8]  = *(const float4*)(r + 8);
    *(float4*)&win[12] = *(const float4*)(r + 12);
#pragma unroll
    for (int j = 0; j < 9; ++j) {
      float wt = w3[i * 9 + j];
#pragma unroll
      for (int k = 0; k < 8; ++k) o[k] += win[j + k] * wt;
    }
  }
  unsigned short ob[8];
#pragma unroll
  for (int k = 0; k < 8; ++k) ob[k] = to_bf16(o[k]);
  *(uint4*)(plane + (2 + e) * 64 + w0) = *(const uint4*)ob;
}

// ---------------------------------------------------------------------------
// k_t4k: (5,1) grouped conv (groups of 4 channels) over zero-padded t3 planes.
// ---------------------------------------------------------------------------
__global__ __launch_bounds__(256) void k_t4k(const unsigned short* __restrict__ t3g,
                                             const float* __restrict__ p4,
                                             unsigned short* __restrict__ t4b) {
  const int nc = blockIdx.x;
  const int c = nc & 255;
  const int tid = threadIdx.x;
  const int e = tid >> 3, w0 = (tid & 7) * 8;
  const float* w4 = p4 + c * 20;
  float acc[8];
#pragma unroll
  for (int k = 0; k < 8; ++k) acc[k] = 0.f;
#pragma unroll
  for (int ci = 0; ci < 4; ++ci) {
    const unsigned short* plane = t3g + (size_t)((nc & ~3) + ci) * 2304;
#pragma unroll
    for (int u = 0; u < 5; ++u) {
      uint4 v = *(const uint4*)(plane + (e + u) * 64 + w0);
      const unsigned short* vs = (const unsigned short*)&v;
      float wv = w4[ci * 5 + u];
#pragma unroll
      for (int k = 0; k < 8; ++k) acc[k] += from_bf16(vs[k]) * wv;
    }
  }
  unsigned short ob[8];
#pragma unroll
  for (int k = 0; k < 8; ++k) ob[k] = to_bf16(acc[k]);
  *(uint4*)(t4b + (size_t)nc * 2048 + e * 64 + w0) = *(const uint4*)ob;
}

// ---------------------------------------------------------------------------
// p5 [2048][768] f32 -> p5t [768][2048] bf16 (transpose + convert)
// ---------------------------------------------------------------------------
__global__ __launch_bounds__(256) void k_p5t(const float* __restrict__ p5,
                                             unsigned short* __restrict__ p5t) {
  const int f0 = blockIdx.x * 64;
  const int k0 = blockIdx.y * 64;
  const int tid = threadIdx.x;
  __shared__ __align__(16) unsigned short ls[64][264];
  int fl = tid & 63, k4 = tid >> 6;
  for (int i = 0; i < 16; ++i) {
    int kl = k4 * 16 + i;
    ls[fl][kl] = to_bf16(p5[(size_t)(k0 + kl) * F + f0 + fl]);
  }
  __syncthreads();
#pragma unroll
  for (int j = 0; j < 2; ++j) {
    int chunk = tid + 256 * j;
    int row = chunk >> 3, slot = chunk & 7;
    *(uint4*)(p5t + (size_t)(f0 + row) * K5 + k0 + slot * 8) = *(const uint4*)&ls[row][slot * 8];
  }
}

// ---------------------------------------------------------------------------
// x [n][c][h][w] f32 -> xt [n][64 + h*64+w + 64][c] bf16, zero pads
// ---------------------------------------------------------------------------
__global__ __launch_bounds__(256) void k_xt(const float* __restrict__ x,
                                            unsigned short* __restrict__ xt) {
  const int hi = blockIdx.x;   // 0..65
  const int n = blockIdx.y;
  const int tid = threadIdx.x;
  unsigned short* dst = xt + ((size_t)n * XROWS + hi * 64) * C;
  if (hi == 0 || hi == 65) {
    uint4 z = make_uint4(0, 0, 0, 0);
    uint4* d4 = (uint4*)dst;
#pragma unroll
    for (int i = 0; i < 8; ++i) d4[tid + 256 * i] = z;
    return;
  }
  const int h = hi - 1;
  __shared__ __align__(16) unsigned short ls[64][264];
  const float* xp = x + ((size_t)n * C) * HW + h * 64;
  int w = tid & 63, c4 = tid >> 6;
  for (int i = 0; i < 64; ++i) {
    int c = c4 * 64 + i;
    ls[w][c] = to_bf16(xp[(size_t)c * HW + w]);
  }
  __syncthreads();
#pragma unroll
  for (int j = 0; j < 8; ++j) {
    int chunk = tid + 256 * j;          // 2048 chunks of 16B
    int row = chunk >> 5, slot = chunk & 31;
    *(uint4*)(dst + row * C + slot * 8) = *(const uint4*)&ls[row][slot * 8];
  }
}

// ---------------------------------------------------------------------------
// k_t5m: t5b[4096][768] bf16 = t4b[4096][2048]bf16 x p5t^T.  64x64 tile,
// 32x32x16 MFMA (1 frag/wave), single-buffer, XCD-swizzled grid.
// Output stored bf16 (halves t5 round-trip; t6 re-rounds to bf16 anyway).
// ---------------------------------------------------------------------------
__global__ __launch_bounds__(256) void k_t5m(const unsigned short* __restrict__ A,
                                             const unsigned short* __restrict__ Bt,
                                             unsigned short* __restrict__ Cout) {
  const int bid = blockIdx.x;
  const int wg = (bid & 7) * 96 + (bid >> 3);   // bijective: 768 = 8*96
  const int nt = wg % 12;
  const int mt = wg / 12;
  const int n0 = nt * 64;
  const int m0 = mt * 64;
  const int tid = threadIdx.x;
  const int lane = tid & 63;
  const int wave = tid >> 6;
  const int wm = wave >> 1, wn = wave & 1;
  __shared__ __align__(16) short As[4096];
  __shared__ __align__(16) short Bs[4096];
  f32x16 acc = {};
  const int lr = lane >> 3;
  const int ls = lane & 7;

  for (int k0 = 0; k0 < K5; k0 += 64) {
#pragma unroll
    for (int i = 0; i < 2; ++i) {
      int inst = wave * 2 + i;       // 0..7
      int r = inst * 8 + lr;         // 0..63
      int sw = ls ^ (r & 7);
      gload16((const char*)(A + (size_t)(m0 + r) * K5 + k0) + sw * 16,
              (char*)As + inst * 1024);
      gload16((const char*)(Bt + (size_t)(n0 + r) * K5 + k0) + sw * 16,
              (char*)Bs + inst * 1024);
    }
    __syncthreads();
#pragma unroll
    for (int kq = 0; kq < 4; ++kq) {
      int arow = wm * 32 + (lane & 31);
      int abyte = (arow * 128 + kq * 32 + ((lane >> 5) * 16)) ^ ((arow & 7) << 4);
      s16x8 af = *(const s16x8*)((const char*)As + abyte);
      int brow = wn * 32 + (lane & 31);
      int bbyte = (brow * 128 + kq * 32 + ((lane >> 5) * 16)) ^ ((brow & 7) << 4);
      s16x8 bf = *(const s16x8*)((const char*)Bs + bbyte);
      acc = __builtin_amdgcn_mfma_f32_32x32x16_bf16(af, bf, acc, 0, 0, 0);
    }
    __syncthreads();
  }
  const int col = n0 + wn * 32 + (lane & 31);
#pragma unroll
  for (int r = 0; r < 16; ++r) {
    int grow = m0 + wm * 32 + (r & 3) + 8 * (r >> 2) + 4 * (lane >> 5);
    Cout[(size_t)grow * F + col] = to_bf16(acc[r]);
  }
}

// ---------------------------------------------------------------------------
// k_t6: t5b bf16 -> 3-tap dw conv (original f order) -> scale -> bf16, f' order
// f' = kk*256 + c2  (f = 3*c2 + kk)
// ---------------------------------------------------------------------------
__global__ __launch_bounds__(256) void k_t6(const unsigned short* __restrict__ t5b,
                                            const float* __restrict__ p6,
                                            unsigned short* __restrict__ t6b) {
  int idx = blockIdx.x * 256 + threadIdx.x;
  if (idx >= NB * C * F) return;
  int fp = idx % F;
  int nc = idx / F;
  int c = nc & 255;
  int c2 = fp & 255;
  int kk = fp >> 8;
  int f = 3 * c2 + kk;
  const unsigned short* row = t5b + (size_t)nc * F;
  const float* wt = p6 + c * 3;
  float acc = from_bf16(row[f]) * wt[1];
  if (f > 0) acc += from_bf16(row[f - 1]) * wt[0];
  if (f < F - 1) acc += from_bf16(row[f + 1]) * wt[2];
  t6b[idx] = to_bf16(acc * 0.03608439182435161f);
}

// ---------------------------------------------------------------------------
// k_outm: out[n][256][4096] f32 = t6b[n][256][768] x B' (from xt, shifted
// rows). 128x256 tile, 512 thr / 8 waves (2M x 4N, wave-tile 64x64),
// 32x32x16 MFMA, single-buffer 48 KB LDS -> 2 blocks/CU co-resident
// (4 waves/SIMD): cross-block TLP hides prologue/epilogue/barrier stalls.
// Grid 512 blocks, XCD-swizzled (each XCD owns 2 n-slices).
// ---------------------------------------------------------------------------
__global__ __launch_bounds__(512, 4) void k_outm(const unsigned short* __restrict__ t6b,
                                                 const unsigned short* __restrict__ xt,
                                                 float* __restrict__ outp) {
  const int bid = blockIdx.x;
  const int wg = (bid & 7) * 64 + (bid >> 3);   // bijective: 512 = 8*64
  const int n  = wg >> 5;                       // 16 n, 32 tiles each
  const int tile = wg & 31;
  const int p0 = (tile & 15) * 256;             // 16 p-tiles
  const int m0 = (tile >> 4) * 128;             // 2 m-tiles
  const int tid = threadIdx.x;
  const int lane = tid & 63;
  const int wid = tid >> 6;                     // 0..7
  const int wm = wid >> 2;                      // 0..1 (64-row half of 128)
  const int wn = wid & 3;                       // 0..3 (64-col quarter of 256)
  __shared__ __align__(16) short As[8192];      // 128x64 bf16 = 16 KB
  __shared__ __align__(16) short Bs[16384];     // 256x64 bf16 = 32 KB
  f32x16 acc[2][2] = {};
  const unsigned short* Abase = t6b + (size_t)(n * C) * F + m0 * F;
  const unsigned short* Xbase = xt + (size_t)n * XROWS * C;

  for (int kt = 0; kt < 12; ++kt) {
    const int k0 = kt * 64;
    const int kk = k0 >> 8, c20 = k0 & 255;
    // stage A: 1024 chunks of 16 B (2/thread); B: 2048 chunks (4/thread)
#pragma unroll
    for (int i = 0; i < 2; ++i) {
      int chunk = i * 512 + tid;
      int r = chunk >> 3, sl = chunk & 7, sw = sl ^ (r & 7);
      gload16((const char*)(Abase + (size_t)r * F + k0) + sw * 16,
              (char*)As + chunk * 16);
    }
#pragma unroll
    for (int i = 0; i < 4; ++i) {
      int chunk = i * 512 + tid;
      int r = chunk >> 3, sl = chunk & 7, sw = sl ^ (r & 7);
      gload16((const char*)(Xbase + (size_t)(p0 + r + (kk << 6)) * C + c20) + sw * 16,
              (char*)Bs + chunk * 16);
    }
    __syncthreads();
#pragma unroll
    for (int kq = 0; kq < 4; ++kq) {
      s16x8 af[2], bf[2];
#pragma unroll
      for (int mi = 0; mi < 2; ++mi) {
        int row = wm * 64 + mi * 32 + (lane & 31);
        int byte = (row * 128 + kq * 32 + ((lane >> 5) * 16)) ^ ((row & 7) << 4);
        af[mi] = *(const s16x8*)((const char*)As + byte);
      }
#pragma unroll
      for (int ni = 0; ni < 2; ++ni) {
        int row = wn * 64 + ni * 32 + (lane & 31);
        int byte = (row * 128 + kq * 32 + ((lane >> 5) * 16)) ^ ((row & 7) << 4);
        bf[ni] = *(const s16x8*)((const char*)Bs + byte);
      }
#pragma unroll
      for (int mi = 0; mi < 2; ++mi)
#pragma unroll
        for (int ni = 0; ni < 2; ++ni)
          acc[mi][ni] = __builtin_amdgcn_mfma_f32_32x32x16_bf16(af[mi], bf[ni], acc[mi][ni], 0, 0, 0);
    }
    __syncthreads();
  }
  float* obase = outp + ((size_t)(n * C) + m0) * HW;
#pragma unroll
  for (int mi = 0; mi < 2; ++mi) {
#pragma unroll
    for (int ni = 0; ni < 2; ++ni) {
      int gcol = p0 + wn * 64 + ni * 32 + (lane & 31);
#pragma unroll
      for (int r = 0; r < 16; ++r) {
        int grow = wm * 64 + mi * 32 + (r & 3) + 8 * (r >> 2) + 4 * (lane >> 5);
        obase[(size_t)grow * HW + gcol] = acc[mi][ni][r];
      }
    }
  }
}

extern "C" void kernel_launch(void* const* d_in, const int* in_sizes, int n_in,
                              void* d_out, int out_size, void* d_ws, size_t ws_size,
                              hipStream_t stream) {
  (void)in_sizes; (void)n_in; (void)out_size; (void)ws_size;
  const float* x  = (const float*)d_in[0];
  const float* p1 = (const float*)d_in[1];
  const float* p3 = (const float*)d_in[2];
  const float* p4 = (const float*)d_in[3];
  const float* p5 = (const float*)d_in[4];
  const float* p6 = (const float*)d_in[5];
  float* out = (float*)d_out;

  char* ws = (char*)d_ws;
  // Lifetime-overlaid workspace (peak ~45 MB):
  //  [0      , 18.87M): t3g  (k_t3 -> k_t4k); then t6b at [0, 6.29M) (k_t6 ->)
  //                      and xt at [6.29M, 40.89M) (k_xt -> k_outm)
  //  [18.87M , 35.65M): t1b  (k_t1 -> k_t3); then t4b (k_t4k -> k_t5m)
  //  [35.65M , 38.80M): p5t  (k_p5t -> k_t5m)
  //  [38.80M , 45.1M):  t5b bf16 (k_t5m -> k_t6; dead before k_xt writes here)
  unsigned short* t3g = (unsigned short*)ws;
  unsigned short* t1b = (unsigned short*)(ws + 18874368);
  unsigned short* t4b = (unsigned short*)(ws + 18874368);
  unsigned short* p5t = (unsigned short*)(ws + 35651584);
  unsigned short* t5b = (unsigned short*)(ws + 38797312);
  unsigned short* t6b = (unsigned short*)ws;
  unsigned short* xt  = (unsigned short*)(ws + 6291456);

  k_t1 <<<dim3(NB * C), 256, 0, stream>>>(x, p1, t1b);
  k_t3 <<<dim3(NB * C), 256, 0, stream>>>(t1b, p3, t3g);
  k_t4k<<<dim3(NB * C), 256, 0, stream>>>(t3g, p4, t4b);
  k_p5t<<<dim3(12, 32), 256, 0, stream>>>(p5, p5t);
  k_t5m<<<dim3(768), 256, 0, stream>>>(t4b, p5t, t5b);
  k_t6 <<<dim3((NB * C * F + 255) / 256), 256, 0, stream>>>(t5b, p6, t6b);
  k_xt <<<dim3(66, NB), 256, 0, stream>>>(x, xt);
  k_outm<<<dim3(512), 512, 0, stream>>>(t6b, xt, out);
}

// Round 14
// 147.760 us; speedup vs baseline: 1.2135x; 1.0553x over previous
//
#include <hip/hip_runtime.h>

#define NB 16
#define C  256
#define H  64
#define W  64
#define E  32
#define F  768
#define HW 4096
#define K5 2048
#define XROWS 4224   // 64 pad + 4096 + 64 pad

typedef __attribute__((ext_vector_type(4))) float f32x4;
typedef __attribute__((ext_vector_type(16))) float f32x16;
typedef __attribute__((ext_vector_type(8))) short s16x8;

__device__ inline unsigned short to_bf16(float f) {
  union { float f; unsigned u; } v; v.f = f;
  unsigned u = v.u;
  u += 0x7fff + ((u >> 16) & 1);
  return (unsigned short)(u >> 16);
}

__device__ inline float from_bf16(unsigned short s) {
  union { unsigned u; float f; } v; v.u = ((unsigned)s) << 16;
  return v.f;
}

__device__ inline void gload16(const void* g, void* l) {
  __builtin_amdgcn_global_load_lds((const __attribute__((address_space(1))) unsigned int*)g,
                                   (__attribute__((address_space(3))) unsigned int*)l, 16, 0, 0);
}

// ---------------------------------------------------------------------------
// k_t13: fused t1 (einsum over h) + t3 (9x9 depthwise). One block per (n,c).
// t1 kept f32 in LDS (no global round-trip, one less bf16 rounding).
// The 9x9 conv is entirely within the (e,w) plane -> zero duplication.
// LDS 20.9 KB -> 7 blocks/CU; grid 4096 = 16 blocks/CU of work.
// Output plane [36][64] bf16 with 2 zero halo rows top/bottom (t4 branch-free).
// ---------------------------------------------------------------------------
__global__ __launch_bounds__(256) void k_t13(const float* __restrict__ x,
                                             const float* __restrict__ p1,
                                             const float* __restrict__ p3,
                                             unsigned short* __restrict__ t3g) {
  const int nc = blockIdx.x;
  const int c = nc & 255;
  const int tid = threadIdx.x;
  __shared__ __align__(16) float p1t[32][68];  // p1t[e][h], 8.7 KB
  __shared__ __align__(16) float t1s[40][76];  // 12.2 KB, zero borders
  for (int i = tid; i < 40 * 76; i += 256) (&t1s[0][0])[i] = 0.f;
  for (int i = tid; i < 2048; i += 256) {
    int h = i >> 5, e = i & 31;
    p1t[e][h] = p1[i];
  }
  __syncthreads();
  // ---- t1: thread (e0 = tid>>6, w = tid&63) computes 8 e-rows
  {
    const int w = tid & 63;
    const int e0 = tid >> 6;
    const float* xp = x + (size_t)nc * HW;
    float acc[8] = {0.f, 0.f, 0.f, 0.f, 0.f, 0.f, 0.f, 0.f};
#pragma unroll
    for (int hb = 0; hb < 4; ++hb) {
      float xv[16];
#pragma unroll
      for (int j = 0; j < 16; ++j) xv[j] = xp[(hb * 16 + j) * 64 + w];
#pragma unroll
      for (int i = 0; i < 8; ++i) {
        const float* pr = &p1t[e0 + 4 * i][hb * 16];
#pragma unroll
        for (int jb = 0; jb < 4; ++jb) {
          float4 pv = *(const float4*)(pr + jb * 4);
          acc[i] += xv[jb * 4 + 0] * pv.x + xv[jb * 4 + 1] * pv.y +
                    xv[jb * 4 + 2] * pv.z + xv[jb * 4 + 3] * pv.w;
        }
      }
    }
#pragma unroll
    for (int i = 0; i < 8; ++i) t1s[4 + e0 + 4 * i][4 + w] = acc[i];
  }
  __syncthreads();
  // ---- t3: 9x9 depthwise, branch-free register window
  unsigned short* plane = t3g + (size_t)nc * 2304;  // 36*64
  if (tid < 32) {
    static const int zr[4] = {0, 1, 34, 35};
    int row = zr[tid >> 3], col = (tid & 7) * 8;
    uint4 z = make_uint4(0, 0, 0, 0);
    *(uint4*)(plane + row * 64 + col) = z;
  }
  const int e = tid >> 3, w0 = (tid & 7) * 8;
  const float* w3 = p3 + c * 81;
  float o[8];
#pragma unroll
  for (int k = 0; k < 8; ++k) o[k] = 0.f;
#pragma unroll
  for (int i = 0; i < 9; ++i) {
    float win[16];
    const float* r = &t1s[e + i][w0];
    *(float4*)&win[0]  = *(const float4*)(r);
    *(float4*)&win[4]  = *(const float4*)(r + 4);
    *(float4*)&win[8]  = *(const float4*)(r + 8);
    *(float4*)&win[12] = *(const float4*)(r + 12);
#pragma unroll
    for (int j = 0; j < 9; ++j) {
      float wt = w3[i * 9 + j];
#pragma unroll
      for (int k = 0; k < 8; ++k) o[k] += win[j + k] * wt;
    }
  }
  unsigned short ob[8];
#pragma unroll
  for (int k = 0; k < 8; ++k) ob[k] = to_bf16(o[k]);
  *(uint4*)(plane + (2 + e) * 64 + w0) = *(const uint4*)ob;
}

// ---------------------------------------------------------------------------
// k_t4k: (5,1) grouped conv (groups of 4 channels) over zero-padded t3 planes.
// ---------------------------------------------------------------------------
__global__ __launch_bounds__(256) void k_t4k(const unsigned short* __restrict__ t3g,
                                             const float* __restrict__ p4,
                                             unsigned short* __restrict__ t4b) {
  const int nc = blockIdx.x;
  const int c = nc & 255;
  const int tid = threadIdx.x;
  const int e = tid >> 3, w0 = (tid & 7) * 8;
  const float* w4 = p4 + c * 20;
  float acc[8];
#pragma unroll
  for (int k = 0; k < 8; ++k) acc[k] = 0.f;
#pragma unroll
  for (int ci = 0; ci < 4; ++ci) {
    const unsigned short* plane = t3g + (size_t)((nc & ~3) + ci) * 2304;
#pragma unroll
    for (int u = 0; u < 5; ++u) {
      uint4 v = *(const uint4*)(plane + (e + u) * 64 + w0);
      const unsigned short* vs = (const unsigned short*)&v;
      float wv = w4[ci * 5 + u];
#pragma unroll
      for (int k = 0; k < 8; ++k) acc[k] += from_bf16(vs[k]) * wv;
    }
  }
  unsigned short ob[8];
#pragma unroll
  for (int k = 0; k < 8; ++k) ob[k] = to_bf16(acc[k]);
  *(uint4*)(t4b + (size_t)nc * 2048 + e * 64 + w0) = *(const uint4*)ob;
}

// ---------------------------------------------------------------------------
// p5 [2048][768] f32 -> p5t [768][2048] bf16 (transpose + convert)
// ---------------------------------------------------------------------------
__global__ __launch_bounds__(256) void k_p5t(const float* __restrict__ p5,
                                             unsigned short* __restrict__ p5t) {
  const int f0 = blockIdx.x * 64;
  const int k0 = blockIdx.y * 64;
  const int tid = threadIdx.x;
  __shared__ __align__(16) unsigned short ls[64][264];
  int fl = tid & 63, k4 = tid >> 6;
  for (int i = 0; i < 16; ++i) {
    int kl = k4 * 16 + i;
    ls[fl][kl] = to_bf16(p5[(size_t)(k0 + kl) * F + f0 + fl]);
  }
  __syncthreads();
#pragma unroll
  for (int j = 0; j < 2; ++j) {
    int chunk = tid + 256 * j;
    int row = chunk >> 3, slot = chunk & 7;
    *(uint4*)(p5t + (size_t)(f0 + row) * K5 + k0 + slot * 8) = *(const uint4*)&ls[row][slot * 8];
  }
}

// ---------------------------------------------------------------------------
// x [n][c][h][w] f32 -> xt [n][64 + h*64+w + 64][c] bf16, zero pads
// ---------------------------------------------------------------------------
__global__ __launch_bounds__(256) void k_xt(const float* __restrict__ x,
                                            unsigned short* __restrict__ xt) {
  const int hi = blockIdx.x;   // 0..65
  const int n = blockIdx.y;
  const int tid = threadIdx.x;
  unsigned short* dst = xt + ((size_t)n * XROWS + hi * 64) * C;
  if (hi == 0 || hi == 65) {
    uint4 z = make_uint4(0, 0, 0, 0);
    uint4* d4 = (uint4*)dst;
#pragma unroll
    for (int i = 0; i < 8; ++i) d4[tid + 256 * i] = z;
    return;
  }
  const int h = hi - 1;
  __shared__ __align__(16) unsigned short ls[64][264];
  const float* xp = x + ((size_t)n * C) * HW + h * 64;
  int w = tid & 63, c4 = tid >> 6;
  for (int i = 0; i < 64; ++i) {
    int c = c4 * 64 + i;
    ls[w][c] = to_bf16(xp[(size_t)c * HW + w]);
  }
  __syncthreads();
#pragma unroll
  for (int j = 0; j < 8; ++j) {
    int chunk = tid + 256 * j;          // 2048 chunks of 16B
    int row = chunk >> 5, slot = chunk & 31;
    *(uint4*)(dst + row * C + slot * 8) = *(const uint4*)&ls[row][slot * 8];
  }
}

// ---------------------------------------------------------------------------
// k_t5m: t5b[4096][768] bf16 = t4b[4096][2048]bf16 x p5t^T.  64x64 tile,
// BK=128 (16 k-tiles, half the barriers), 32x32x16 MFMA, 32 KB LDS
// (3 blocks/CU), 16-slot XOR swizzle, XCD-swizzled grid.
// ---------------------------------------------------------------------------
__global__ __launch_bounds__(256) void k_t5m(const unsigned short* __restrict__ A,
                                             const unsigned short* __restrict__ Bt,
                                             unsigned short* __restrict__ Cout) {
  const int bid = blockIdx.x;
  const int wg = (bid & 7) * 96 + (bid >> 3);   // bijective: 768 = 8*96
  const int nt = wg % 12;
  const int mt = wg / 12;
  const int n0 = nt * 64;
  const int m0 = mt * 64;
  const int tid = threadIdx.x;
  const int lane = tid & 63;
  const int wave = tid >> 6;
  const int wm = wave >> 1, wn = wave & 1;
  __shared__ __align__(16) short As[8192];      // 64 x 128 bf16
  __shared__ __align__(16) short Bs[8192];
  f32x16 acc = {};

  for (int k0 = 0; k0 < K5; k0 += 128) {
#pragma unroll
    for (int i = 0; i < 4; ++i) {
      int chunk = i * 256 + tid;       // 0..1023: row r (0..63), slot sl (0..15)
      int r = chunk >> 4, sl = chunk & 15;
      int sw = sl ^ (r & 15);
      gload16((const char*)(A + (size_t)(m0 + r) * K5 + k0) + sw * 16,
              (char*)As + chunk * 16);
      gload16((const char*)(Bt + (size_t)(n0 + r) * K5 + k0) + sw * 16,
              (char*)Bs + chunk * 16);
    }
    __syncthreads();
#pragma unroll
    for (int kq = 0; kq < 8; ++kq) {
      int arow = wm * 32 + (lane & 31);
      int aslot = (kq * 2 + (lane >> 5)) ^ (arow & 15);
      s16x8 af = *(const s16x8*)((const char*)As + arow * 256 + aslot * 16);
      int brow = wn * 32 + (lane & 31);
      int bslot = (kq * 2 + (lane >> 5)) ^ (brow & 15);
      s16x8 bf = *(const s16x8*)((const char*)Bs + brow * 256 + bslot * 16);
      acc = __builtin_amdgcn_mfma_f32_32x32x16_bf16(af, bf, acc, 0, 0, 0);
    }
    __syncthreads();
  }
  const int col = n0 + wn * 32 + (lane & 31);
#pragma unroll
  for (int r = 0; r < 16; ++r) {
    int grow = m0 + wm * 32 + (r & 3) + 8 * (r >> 2) + 4 * (lane >> 5);
    Cout[(size_t)grow * F + col] = to_bf16(acc[r]);
  }
}

// ---------------------------------------------------------------------------
// k_t6: t5b bf16 -> 3-tap dw conv (original f order) -> scale -> bf16, f' order
// f' = kk*256 + c2  (f = 3*c2 + kk)
// ---------------------------------------------------------------------------
__global__ __launch_bounds__(256) void k_t6(const unsigned short* __restrict__ t5b,
                                            const float* __restrict__ p6,
                                            unsigned short* __restrict__ t6b) {
  int idx = blockIdx.x * 256 + threadIdx.x;
  if (idx >= NB * C * F) return;
  int fp = idx % F;
  int nc = idx / F;
  int c = nc & 255;
  int c2 = fp & 255;
  int kk = fp >> 8;
  int f = 3 * c2 + kk;
  const unsigned short* row = t5b + (size_t)nc * F;
  const float* wt = p6 + c * 3;
  float acc = from_bf16(row[f]) * wt[1];
  if (f > 0) acc += from_bf16(row[f - 1]) * wt[0];
  if (f < F - 1) acc += from_bf16(row[f + 1]) * wt[2];
  t6b[idx] = to_bf16(acc * 0.03608439182435161f);
}

// ---------------------------------------------------------------------------
// k_outm: out[n][256][4096] f32 = t6b[n][256][768] x B' (from xt, shifted
// rows). 128x256 tile, 512 thr / 8 waves (2M x 4N, wave-tile 64x64),
// 32x32x16 MFMA, single-buffer 48 KB LDS -> 2 blocks/CU co-resident.
// ---------------------------------------------------------------------------
__global__ __launch_bounds__(512, 4) void k_outm(const unsigned short* __restrict__ t6b,
                                                 const unsigned short* __restrict__ xt,
                                                 float* __restrict__ outp) {
  const int bid = blockIdx.x;
  const int wg = (bid & 7) * 64 + (bid >> 3);   // bijective: 512 = 8*64
  const int n  = wg >> 5;                       // 16 n, 32 tiles each
  const int tile = wg & 31;
  const int p0 = (tile & 15) * 256;             // 16 p-tiles
  const int m0 = (tile >> 4) * 128;             // 2 m-tiles
  const int tid = threadIdx.x;
  const int lane = tid & 63;
  const int wid = tid >> 6;                     // 0..7
  const int wm = wid >> 2;                      // 0..1
  const int wn = wid & 3;                       // 0..3
  __shared__ __align__(16) short As[8192];      // 128x64 bf16 = 16 KB
  __shared__ __align__(16) short Bs[16384];     // 256x64 bf16 = 32 KB
  f32x16 acc[2][2] = {};
  const unsigned short* Abase = t6b + (size_t)(n * C) * F + m0 * F;
  const unsigned short* Xbase = xt + (size_t)n * XROWS * C;

  for (int kt = 0; kt < 12; ++kt) {
    const int k0 = kt * 64;
    const int kk = k0 >> 8, c20 = k0 & 255;
#pragma unroll
    for (int i = 0; i < 2; ++i) {
      int chunk = i * 512 + tid;
      int r = chunk >> 3, sl = chunk & 7, sw = sl ^ (r & 7);
      gload16((const char*)(Abase + (size_t)r * F + k0) + sw * 16,
              (char*)As + chunk * 16);
    }
#pragma unroll
    for (int i = 0; i < 4; ++i) {
      int chunk = i * 512 + tid;
      int r = chunk >> 3, sl = chunk & 7, sw = sl ^ (r & 7);
      gload16((const char*)(Xbase + (size_t)(p0 + r + (kk << 6)) * C + c20) + sw * 16,
              (char*)Bs + chunk * 16);
    }
    __syncthreads();
#pragma unroll
    for (int kq = 0; kq < 4; ++kq) {
      s16x8 af[2], bf[2];
#pragma unroll
      for (int mi = 0; mi < 2; ++mi) {
        int row = wm * 64 + mi * 32 + (lane & 31);
        int byte = (row * 128 + kq * 32 + ((lane >> 5) * 16)) ^ ((row & 7) << 4);
        af[mi] = *(const s16x8*)((const char*)As + byte);
      }
#pragma unroll
      for (int ni = 0; ni < 2; ++ni) {
        int row = wn * 64 + ni * 32 + (lane & 31);
        int byte = (row * 128 + kq * 32 + ((lane >> 5) * 16)) ^ ((row & 7) << 4);
        bf[ni] = *(const s16x8*)((const char*)Bs + byte);
      }
#pragma unroll
      for (int mi = 0; mi < 2; ++mi)
#pragma unroll
        for (int ni = 0; ni < 2; ++ni)
          acc[mi][ni] = __builtin_amdgcn_mfma_f32_32x32x16_bf16(af[mi], bf[ni], acc[mi][ni], 0, 0, 0);
    }
    __syncthreads();
  }
  float* obase = outp + ((size_t)(n * C) + m0) * HW;
#pragma unroll
  for (int mi = 0; mi < 2; ++mi) {
#pragma unroll
    for (int ni = 0; ni < 2; ++ni) {
      int gcol = p0 + wn * 64 + ni * 32 + (lane & 31);
#pragma unroll
      for (int r = 0; r < 16; ++r) {
        int grow = wm * 64 + mi * 32 + (r & 3) + 8 * (r >> 2) + 4 * (lane >> 5);
        obase[(size_t)grow * HW + gcol] = acc[mi][ni][r];
      }
    }
  }
}

extern "C" void kernel_launch(void* const* d_in, const int* in_sizes, int n_in,
                              void* d_out, int out_size, void* d_ws, size_t ws_size,
                              hipStream_t stream) {
  (void)in_sizes; (void)n_in; (void)out_size; (void)ws_size;
  const float* x  = (const float*)d_in[0];
  const float* p1 = (const float*)d_in[1];
  const float* p3 = (const float*)d_in[2];
  const float* p4 = (const float*)d_in[3];
  const float* p5 = (const float*)d_in[4];
  const float* p6 = (const float*)d_in[5];
  float* out = (float*)d_out;

  char* ws = (char*)d_ws;
  // Lifetime-overlaid workspace (peak ~45 MB):
  //  [0      , 18.87M): t3g  (k_t13 -> k_t4k); then t6b at [0, 6.29M) (k_t6 ->)
  //                      and xt at [6.29M, 40.89M) (k_xt -> k_outm)
  //  [18.87M , 35.65M): t4b  (k_t4k -> k_t5m)
  //  [35.65M , 38.80M): p5t  (k_p5t -> k_t5m)
  //  [38.80M , 45.1M):  t5b bf16 (k_t5m -> k_t6; dead before k_xt writes here)
  unsigned short* t3g = (unsigned short*)ws;
  unsigned short* t4b = (unsigned short*)(ws + 18874368);
  unsigned short* p5t = (unsigned short*)(ws + 35651584);
  unsigned short* t5b = (unsigned short*)(ws + 38797312);
  unsigned short* t6b = (unsigned short*)ws;
  unsigned short* xt  = (unsigned short*)(ws + 6291456);

  k_t13<<<dim3(NB * C), 256, 0, stream>>>(x, p1, p3, t3g);
  k_t4k<<<dim3(NB * C), 256, 0, stream>>>(t3g, p4, t4b);
  k_p5t<<<dim3(12, 32), 256, 0, stream>>>(p5, p5t);
  k_t5m<<<dim3(768), 256, 0, stream>>>(t4b, p5t, t5b);
  k_t6 <<<dim3((NB * C * F + 255) / 256), 256, 0, stream>>>(t5b, p6, t6b);
  k_xt <<<dim3(66, NB), 256, 0, stream>>>(x, xt);
  k_outm<<<dim3(512), 512, 0, stream>>>(t6b, xt, out);
}

// Round 15
// 133.555 us; speedup vs baseline: 1.3426x; 1.1064x over previous
//
#include <hip/hip_runtime.h>

#define NB 16
#define C  256
#define H  64
#define W  64
#define E  32
#define F  768
#define HW 4096
#define K5 2048
#define XROWS 4224   // 64 pad + 4096 + 64 pad

typedef __attribute__((ext_vector_type(2))) float f32x2;
typedef __attribute__((ext_vector_type(4))) float f32x4;
typedef __attribute__((ext_vector_type(16))) float f32x16;
typedef __attribute__((ext_vector_type(8))) short s16x8;

__device__ inline unsigned short to_bf16(float f) {
  union { float f; unsigned u; } v; v.f = f;
  unsigned u = v.u;
  u += 0x7fff + ((u >> 16) & 1);
  return (unsigned short)(u >> 16);
}

__device__ inline float from_bf16(unsigned short s) {
  union { unsigned u; float f; } v; v.u = ((unsigned)s) << 16;
  return v.f;
}

__device__ inline void gload16(const void* g, void* l) {
  __builtin_amdgcn_global_load_lds((const __attribute__((address_space(1))) unsigned int*)g,
                                   (__attribute__((address_space(3))) unsigned int*)l, 16, 0, 0);
}

// ---------------------------------------------------------------------------
// k_wp: pre-pack p3 weights into aligned f32x2 pairs for k_t13's pk-FMA path.
// Per (c, row i): 20 floats = we[0..4] then wo[0..4]:
//   we[q]=(w[2q],w[2q+1]) q<4, we[4]=(w[8],0); wo[0]=(0,w[0]), wo[q]=(w[2q-1],w[2q]).
// ---------------------------------------------------------------------------
__global__ __launch_bounds__(192) void k_wp(const float* __restrict__ p3,
                                            float* __restrict__ w3p) {
  const int c = blockIdx.x;
  const int t = threadIdx.x;
  if (t >= 180) return;
  const int i = t / 20, s = t % 20;
  const float* wr = p3 + c * 81 + i * 9;
  float v;
  if (s < 10) {
    int q = s >> 1, e = s & 1;
    v = (q < 4) ? wr[2 * q + e] : (e ? 0.f : wr[8]);
  } else {
    int s2 = s - 10, q = s2 >> 1, e = s2 & 1;
    v = (q == 0) ? (e ? wr[0] : 0.f) : wr[2 * (q - 1) + 1 + e];
  }
  w3p[(size_t)(c * 9 + i) * 20 + s] = v;
}

// ---------------------------------------------------------------------------
// k_t13: fused t1 (MFMA) + t3 (9x9 dw, packed f32). One block per (n,c).
// t1: p1^T(32x64) x x(64x64) via 16x16x32 bf16 MFMA; xs bf16 col-unit swizzled.
// t3: per row, 40 v_pk_fma_f32 with aligned window pairs + prepacked weights.
// LDS 20.3 KB -> 7 blocks/CU. Output [36][64] bf16 w/ 2 zero halo rows.
// ---------------------------------------------------------------------------
__global__ __launch_bounds__(256) void k_t13(const float* __restrict__ x,
                                             const float* __restrict__ p1,
                                             const float* __restrict__ w3p,
                                             unsigned short* __restrict__ t3g) {
  const int nc = blockIdx.x;
  const int c = nc & 255;
  const int tid = threadIdx.x;
  const int lane = tid & 63;
  const int wv = tid >> 6;

  __shared__ __align__(16) unsigned short xs[64][64];  // 8 KB, swizzled
  __shared__ __align__(16) float t1s[40][76];          // 12.2 KB, zero borders

  for (int i = tid; i < 40 * 76; i += 256) (&t1s[0][0])[i] = 0.f;

  // A-fragments: p1^T rows=e; lane r=lane&15 -> e=m*16+r, k=kc*32+(lane>>4)*8+j
  s16x8 afr[2][2];
  {
    const int r = lane & 15;
    const int kb = (lane >> 4) * 8;
#pragma unroll
    for (int m = 0; m < 2; ++m)
#pragma unroll
      for (int kc = 0; kc < 2; ++kc) {
        s16x8 tmp;
#pragma unroll
        for (int j = 0; j < 8; ++j)
          tmp[j] = (short)to_bf16(p1[(kc * 32 + kb + j) * 32 + m * 16 + r]);
        afr[m][kc] = tmp;
      }
  }
  // stage x -> xs bf16, col-unit swizzle u ^= (h>>3)&7
  {
    const float* xp = x + (size_t)nc * HW;
#pragma unroll
    for (int t = 0; t < 2; ++t) {
      int uid = tid + 256 * t;
      int h = uid >> 3, uc = uid & 7;
      float4 v0 = *(const float4*)(xp + h * 64 + uc * 8);
      float4 v1 = *(const float4*)(xp + h * 64 + uc * 8 + 4);
      unsigned short b[8] = {to_bf16(v0.x), to_bf16(v0.y), to_bf16(v0.z), to_bf16(v0.w),
                             to_bf16(v1.x), to_bf16(v1.y), to_bf16(v1.z), to_bf16(v1.w)};
      *(uint4*)((char*)&xs[0][0] + h * 128 + ((uc ^ ((h >> 3) & 7)) * 16)) = *(const uint4*)b;
    }
  }
  __syncthreads();
  // ---- t1 via MFMA: wave wv covers cols [16wv, 16wv+16)
  {
    const int wcol = wv * 16 + (lane & 15);
    f32x4 cf[2] = {{0.f, 0.f, 0.f, 0.f}, {0.f, 0.f, 0.f, 0.f}};
#pragma unroll
    for (int kc = 0; kc < 2; ++kc) {
      const int kb = kc * 32 + (lane >> 4) * 8;
      const char* base = (const char*)&xs[0][0] +
                         kb * 128 + (((wcol >> 3) ^ ((kb >> 3) & 7)) * 16) + (wcol & 7) * 2;
      s16x8 bfrag;
#pragma unroll
      for (int j = 0; j < 8; ++j)
        bfrag[j] = *(const short*)(base + j * 128);
      cf[0] = __builtin_amdgcn_mfma_f32_16x16x32_bf16(afr[0][kc], bfrag, cf[0], 0, 0, 0);
      cf[1] = __builtin_amdgcn_mfma_f32_16x16x32_bf16(afr[1][kc], bfrag, cf[1], 0, 0, 0);
    }
#pragma unroll
    for (int m = 0; m < 2; ++m)
#pragma unroll
      for (int q = 0; q < 4; ++q)
        t1s[4 + m * 16 + (lane >> 4) * 4 + q][4 + wcol] = cf[m][q];
  }
  __syncthreads();
  // ---- t3: 9x9 depthwise, packed f32 pairs
  unsigned short* plane = t3g + (size_t)nc * 2304;  // 36*64
  if (tid < 32) {
    static const int zr[4] = {0, 1, 34, 35};
    int row = zr[tid >> 3], col = (tid & 7) * 8;
    uint4 z = make_uint4(0, 0, 0, 0);
    *(uint4*)(plane + row * 64 + col) = z;
  }
  const int e = tid >> 3, w0 = (tid & 7) * 8;
  f32x2 opk[8] = {};
#pragma unroll
  for (int i = 0; i < 9; ++i) {
    const float* r = &t1s[e + i][w0];
    f32x4 v0 = *(const f32x4*)(r);
    f32x4 v1 = *(const f32x4*)(r + 4);
    f32x4 v2 = *(const f32x4*)(r + 8);
    f32x4 v3 = *(const f32x4*)(r + 12);
    f32x2 wa[8];
    wa[0] = __builtin_shufflevector(v0, v0, 0, 1);
    wa[1] = __builtin_shufflevector(v0, v0, 2, 3);
    wa[2] = __builtin_shufflevector(v1, v1, 0, 1);
    wa[3] = __builtin_shufflevector(v1, v1, 2, 3);
    wa[4] = __builtin_shufflevector(v2, v2, 0, 1);
    wa[5] = __builtin_shufflevector(v2, v2, 2, 3);
    wa[6] = __builtin_shufflevector(v3, v3, 0, 1);
    wa[7] = __builtin_shufflevector(v3, v3, 2, 3);
    const f32x2* wp = (const f32x2*)(w3p + (size_t)(c * 9 + i) * 20);
    f32x2 we0 = wp[0], we1 = wp[1], we2 = wp[2], we3 = wp[3], we4 = wp[4];
    f32x2 wo0 = wp[5], wo1 = wp[6], wo2 = wp[7], wo3 = wp[8], wo4 = wp[9];
#pragma unroll
    for (int t = 0; t < 4; ++t) {
      f32x2 aE = opk[2 * t], aO = opk[2 * t + 1];
      aE += wa[t] * we0;         // taps j=0,1
      aE += wa[t + 1] * we1;     // j=2,3
      aE += wa[t + 2] * we2;     // j=4,5
      aE += wa[t + 3] * we3;     // j=6,7
      aE += wa[t + 4] * we4;     // j=8 (+0)
      aO += wa[t] * wo0;         // j=0 (0+)
      aO += wa[t + 1] * wo1;     // j=1,2
      aO += wa[t + 2] * wo2;     // j=3,4
      aO += wa[t + 3] * wo3;     // j=5,6
      aO += wa[t + 4] * wo4;     // j=7,8
      opk[2 * t] = aE;
      opk[2 * t + 1] = aO;
    }
  }
  unsigned short ob[8];
#pragma unroll
  for (int k = 0; k < 8; ++k) ob[k] = to_bf16(opk[k].x + opk[k].y);
  *(uint4*)(plane + (2 + e) * 64 + w0) = *(const uint4*)ob;
}

// ---------------------------------------------------------------------------
// k_t4k: (5,1) grouped conv (groups of 4 channels) over zero-padded t3 planes.
// ---------------------------------------------------------------------------
__global__ __launch_bounds__(256) void k_t4k(const unsigned short* __restrict__ t3g,
                                             const float* __restrict__ p4,
                                             unsigned short* __restrict__ t4b) {
  const int nc = blockIdx.x;
  const int c = nc & 255;
  const int tid = threadIdx.x;
  const int e = tid >> 3, w0 = (tid & 7) * 8;
  const float* w4 = p4 + c * 20;
  float acc[8];
#pragma unroll
  for (int k = 0; k < 8; ++k) acc[k] = 0.f;
#pragma unroll
  for (int ci = 0; ci < 4; ++ci) {
    const unsigned short* plane = t3g + (size_t)((nc & ~3) + ci) * 2304;
#pragma unroll
    for (int u = 0; u < 5; ++u) {
      uint4 v = *(const uint4*)(plane + (e + u) * 64 + w0);
      const unsigned short* vs = (const unsigned short*)&v;
      float wv = w4[ci * 5 + u];
#pragma unroll
      for (int k = 0; k < 8; ++k) acc[k] += from_bf16(vs[k]) * wv;
    }
  }
  unsigned short ob[8];
#pragma unroll
  for (int k = 0; k < 8; ++k) ob[k] = to_bf16(acc[k]);
  *(uint4*)(t4b + (size_t)nc * 2048 + e * 64 + w0) = *(const uint4*)ob;
}

// ---------------------------------------------------------------------------
// p5 [2048][768] f32 -> p5t [768][2048] bf16 (transpose + convert)
// ---------------------------------------------------------------------------
__global__ __launch_bounds__(256) void k_p5t(const float* __restrict__ p5,
                                             unsigned short* __restrict__ p5t) {
  const int f0 = blockIdx.x * 64;
  const int k0 = blockIdx.y * 64;
  const int tid = threadIdx.x;
  __shared__ __align__(16) unsigned short ls[64][264];
  int fl = tid & 63, k4 = tid >> 6;
  for (int i = 0; i < 16; ++i) {
    int kl = k4 * 16 + i;
    ls[fl][kl] = to_bf16(p5[(size_t)(k0 + kl) * F + f0 + fl]);
  }
  __syncthreads();
#pragma unroll
  for (int j = 0; j < 2; ++j) {
    int chunk = tid + 256 * j;
    int row = chunk >> 3, slot = chunk & 7;
    *(uint4*)(p5t + (size_t)(f0 + row) * K5 + k0 + slot * 8) = *(const uint4*)&ls[row][slot * 8];
  }
}

// ---------------------------------------------------------------------------
// x [n][c][h][w] f32 -> xt [n][64 + h*64+w + 64][c] bf16, zero pads
// ---------------------------------------------------------------------------
__global__ __launch_bounds__(256) void k_xt(const float* __restrict__ x,
                                            unsigned short* __restrict__ xt) {
  const int hi = blockIdx.x;   // 0..65
  const int n = blockIdx.y;
  const int tid = threadIdx.x;
  unsigned short* dst = xt + ((size_t)n * XROWS + hi * 64) * C;
  if (hi == 0 || hi == 65) {
    uint4 z = make_uint4(0, 0, 0, 0);
    uint4* d4 = (uint4*)dst;
#pragma unroll
    for (int i = 0; i < 8; ++i) d4[tid + 256 * i] = z;
    return;
  }
  const int h = hi - 1;
  __shared__ __align__(16) unsigned short ls[64][264];
  const float* xp = x + ((size_t)n * C) * HW + h * 64;
  int w = tid & 63, c4 = tid >> 6;
  for (int i = 0; i < 64; ++i) {
    int c = c4 * 64 + i;
    ls[w][c] = to_bf16(xp[(size_t)c * HW + w]);
  }
  __syncthreads();
#pragma unroll
  for (int j = 0; j < 8; ++j) {
    int chunk = tid + 256 * j;          // 2048 chunks of 16B
    int row = chunk >> 5, slot = chunk & 31;
    *(uint4*)(dst + row * C + slot * 8) = *(const uint4*)&ls[row][slot * 8];
  }
}

// ---------------------------------------------------------------------------
// k_t5m: t5b[4096][768] bf16 = t4b[4096][2048]bf16 x p5t^T.  64x64 tile,
// BK=128, 32x32x16 MFMA, 32 KB LDS (3 blocks/CU), 16-slot XOR swizzle.
// ---------------------------------------------------------------------------
__global__ __launch_bounds__(256) void k_t5m(const unsigned short* __restrict__ A,
                                             const unsigned short* __restrict__ Bt,
                                             unsigned short* __restrict__ Cout) {
  const int bid = blockIdx.x;
  const int wg = (bid & 7) * 96 + (bid >> 3);   // bijective: 768 = 8*96
  const int nt = wg % 12;
  const int mt = wg / 12;
  const int n0 = nt * 64;
  const int m0 = mt * 64;
  const int tid = threadIdx.x;
  const int lane = tid & 63;
  const int wave = tid >> 6;
  const int wm = wave >> 1, wn = wave & 1;
  __shared__ __align__(16) short As[8192];      // 64 x 128 bf16
  __shared__ __align__(16) short Bs[8192];
  f32x16 acc = {};

  for (int k0 = 0; k0 < K5; k0 += 128) {
#pragma unroll
    for (int i = 0; i < 4; ++i) {
      int chunk = i * 256 + tid;       // 0..1023: row r (0..63), slot sl (0..15)
      int r = chunk >> 4, sl = chunk & 15;
      int sw = sl ^ (r & 15);
      gload16((const char*)(A + (size_t)(m0 + r) * K5 + k0) + sw * 16,
              (char*)As + chunk * 16);
      gload16((const char*)(Bt + (size_t)(n0 + r) * K5 + k0) + sw * 16,
              (char*)Bs + chunk * 16);
    }
    __syncthreads();
#pragma unroll
    for (int kq = 0; kq < 8; ++kq) {
      int arow = wm * 32 + (lane & 31);
      int aslot = (kq * 2 + (lane >> 5)) ^ (arow & 15);
      s16x8 af = *(const s16x8*)((const char*)As + arow * 256 + aslot * 16);
      int brow = wn * 32 + (lane & 31);
      int bslot = (kq * 2 + (lane >> 5)) ^ (brow & 15);
      s16x8 bf = *(const s16x8*)((const char*)Bs + brow * 256 + bslot * 16);
      acc = __builtin_amdgcn_mfma_f32_32x32x16_bf16(af, bf, acc, 0, 0, 0);
    }
    __syncthreads();
  }
  const int col = n0 + wn * 32 + (lane & 31);
#pragma unroll
  for (int r = 0; r < 16; ++r) {
    int grow = m0 + wm * 32 + (r & 3) + 8 * (r >> 2) + 4 * (lane >> 5);
    Cout[(size_t)grow * F + col] = to_bf16(acc[r]);
  }
}

// ---------------------------------------------------------------------------
// k_t6: t5b bf16 -> 3-tap dw conv (original f order) -> scale -> bf16, f' order
// f' = kk*256 + c2  (f = 3*c2 + kk)
// ---------------------------------------------------------------------------
__global__ __launch_bounds__(256) void k_t6(const unsigned short* __restrict__ t5b,
                                            const float* __restrict__ p6,
                                            unsigned short* __restrict__ t6b) {
  int idx = blockIdx.x * 256 + threadIdx.x;
  if (idx >= NB * C * F) return;
  int fp = idx % F;
  int nc = idx / F;
  int c = nc & 255;
  int c2 = fp & 255;
  int kk = fp >> 8;
  int f = 3 * c2 + kk;
  const unsigned short* row = t5b + (size_t)nc * F;
  const float* wt = p6 + c * 3;
  float acc = from_bf16(row[f]) * wt[1];
  if (f > 0) acc += from_bf16(row[f - 1]) * wt[0];
  if (f < F - 1) acc += from_bf16(row[f + 1]) * wt[2];
  t6b[idx] = to_bf16(acc * 0.03608439182435161f);
}

// ---------------------------------------------------------------------------
// k_outm: out[n][256][4096] f32 = t6b[n][256][768] x B' (from xt, shifted
// rows). 128x256 tile, 512 thr / 8 waves (2M x 4N, wave-tile 64x64),
// 32x32x16 MFMA, single-buffer 48 KB LDS -> 2 blocks/CU co-resident.
// ---------------------------------------------------------------------------
__global__ __launch_bounds__(512, 4) void k_outm(const unsigned short* __restrict__ t6b,
                                                 const unsigned short* __restrict__ xt,
                                                 float* __restrict__ outp) {
  const int bid = blockIdx.x;
  const int wg = (bid & 7) * 64 + (bid >> 3);   // bijective: 512 = 8*64
  const int n  = wg >> 5;                       // 16 n, 32 tiles each
  const int tile = wg & 31;
  const int p0 = (tile & 15) * 256;             // 16 p-tiles
  const int m0 = (tile >> 4) * 128;             // 2 m-tiles
  const int tid = threadIdx.x;
  const int lane = tid & 63;
  const int wid = tid >> 6;                     // 0..7
  const int wm = wid >> 2;                      // 0..1
  const int wn = wid & 3;                       // 0..3
  __shared__ __align__(16) short As[8192];      // 128x64 bf16 = 16 KB
  __shared__ __align__(16) short Bs[16384];     // 256x64 bf16 = 32 KB
  f32x16 acc[2][2] = {};
  const unsigned short* Abase = t6b + (size_t)(n * C) * F + m0 * F;
  const unsigned short* Xbase = xt + (size_t)n * XROWS * C;

  for (int kt = 0; kt < 12; ++kt) {
    const int k0 = kt * 64;
    const int kk = k0 >> 8, c20 = k0 & 255;
#pragma unroll
    for (int i = 0; i < 2; ++i) {
      int chunk = i * 512 + tid;
      int r = chunk >> 3, sl = chunk & 7, sw = sl ^ (r & 7);
      gload16((const char*)(Abase + (size_t)r * F + k0) + sw * 16,
              (char*)As + chunk * 16);
    }
#pragma unroll
    for (int i = 0; i < 4; ++i) {
      int chunk = i * 512 + tid;
      int r = chunk >> 3, sl = chunk & 7, sw = sl ^ (r & 7);
      gload16((const char*)(Xbase + (size_t)(p0 + r + (kk << 6)) * C + c20) + sw * 16,
              (char*)Bs + chunk * 16);
    }
    __syncthreads();
#pragma unroll
    for (int kq = 0; kq < 4; ++kq) {
      s16x8 af[2], bf[2];
#pragma unroll
      for (int mi = 0; mi < 2; ++mi) {
        int row = wm * 64 + mi * 32 + (lane & 31);
        int byte = (row * 128 + kq * 32 + ((lane >> 5) * 16)) ^ ((row & 7) << 4);
        af[mi] = *(const s16x8*)((const char*)As + byte);
      }
#pragma unroll
      for (int ni = 0; ni < 2; ++ni) {
        int row = wn * 64 + ni * 32 + (lane & 31);
        int byte = (row * 128 + kq * 32 + ((lane >> 5) * 16)) ^ ((row & 7) << 4);
        bf[ni] = *(const s16x8*)((const char*)Bs + byte);
      }
#pragma unroll
      for (int mi = 0; mi < 2; ++mi)
#pragma unroll
        for (int ni = 0; ni < 2; ++ni)
          acc[mi][ni] = __builtin_amdgcn_mfma_f32_32x32x16_bf16(af[mi], bf[ni], acc[mi][ni], 0, 0, 0);
    }
    __syncthreads();
  }
  float* obase = outp + ((size_t)(n * C) + m0) * HW;
#pragma unroll
  for (int mi = 0; mi < 2; ++mi) {
#pragma unroll
    for (int ni = 0; ni < 2; ++ni) {
      int gcol = p0 + wn * 64 + ni * 32 + (lane & 31);
#pragma unroll
      for (int r = 0; r < 16; ++r) {
        int grow = wm * 64 + mi * 32 + (r & 3) + 8 * (r >> 2) + 4 * (lane >> 5);
        obase[(size_t)grow * HW + gcol] = acc[mi][ni][r];
      }
    }
  }
}

extern "C" void kernel_launch(void* const* d_in, const int* in_sizes, int n_in,
                              void* d_out, int out_size, void* d_ws, size_t ws_size,
                              hipStream_t stream) {
  (void)in_sizes; (void)n_in; (void)out_size; (void)ws_size;
  const float* x  = (const float*)d_in[0];
  const float* p1 = (const float*)d_in[1];
  const float* p3 = (const float*)d_in[2];
  const float* p4 = (const float*)d_in[3];
  const float* p5 = (const float*)d_in[4];
  const float* p6 = (const float*)d_in[5];
  float* out = (float*)d_out;

  char* ws = (char*)d_ws;
  // Lifetime-overlaid workspace:
  //  [0      , 18.87M): t3g  (k_t13 -> k_t4k); then t6b at [0, 6.29M) and
  //                      xt at [6.29M, 40.89M) (k_xt -> k_outm)
  //  [18.87M , 35.65M): t4b  (k_t4k -> k_t5m)
  //  [35.65M , 38.80M): p5t  (k_p5t -> k_t5m)
  //  [38.80M , 45.10M): t5b bf16 (k_t5m -> k_t6; dead before k_xt overlaps)
  //  [45.10M , 45.29M): w3p (k_wp -> k_t13)
  unsigned short* t3g = (unsigned short*)ws;
  unsigned short* t4b = (unsigned short*)(ws + 18874368);
  unsigned short* p5t = (unsigned short*)(ws + 35651584);
  unsigned short* t5b = (unsigned short*)(ws + 38797312);
  float*          w3p = (float*)(ws + 47290368);
  unsigned short* t6b = (unsigned short*)ws;
  unsigned short* xt  = (unsigned short*)(ws + 6291456);

  k_wp <<<dim3(C), 192, 0, stream>>>(p3, w3p);
  k_t13<<<dim3(NB * C), 256, 0, stream>>>(x, p1, w3p, t3g);
  k_t4k<<<dim3(NB * C), 256, 0, stream>>>(t3g, p4, t4b);
  k_p5t<<<dim3(12, 32), 256, 0, stream>>>(p5, p5t);
  k_t5m<<<dim3(768), 256, 0, stream>>>(t4b, p5t, t5b);
  k_t6 <<<dim3((NB * C * F + 255) / 256), 256, 0, stream>>>(t5b, p6, t6b);
  k_xt <<<dim3(66, NB), 256, 0, stream>>>(x, xt);
  k_outm<<<dim3(512), 512, 0, stream>>>(t6b, xt, out);
}